// Round 1
// baseline (5442.067 us; speedup 1.0000x reference)
//
#include <hip/hip_runtime.h>

#define N_NODES 50000
#define N_EDGES 640000
#define HDIM    128
#define NLAYERS 3

typedef __attribute__((ext_vector_type(4))) float f32x4;
typedef short s16x8 __attribute__((ext_vector_type(8)));
typedef __bf16 bf16v8 __attribute__((ext_vector_type(8)));

static __device__ __forceinline__ unsigned short f2b(float f){
  unsigned int u = __float_as_uint(f);
  unsigned int r = u + 0x7FFFu + ((u >> 16) & 1u);
  return (unsigned short)(r >> 16);
}
static __device__ __forceinline__ float b2f(unsigned short h){
  return __uint_as_float(((unsigned int)h) << 16);
}
static __device__ __forceinline__ float silu_f(float x){
  return x / (1.0f + __expf(-x));
}
static __device__ __forceinline__ f32x4 MFMA(s16x8 a, s16x8 b, f32x4 c){
  return __builtin_amdgcn_mfma_f32_16x16x32_bf16(
      __builtin_bit_cast(bf16v8, a), __builtin_bit_cast(bf16v8, b), c, 0, 0, 0);
}

// A-fragment: transposed weight WT[out][in], out-row = s*16 + (lane&15),
// k = kk*32 + (j>>2)*16 + q*4 + (j&3)  (the shared k-map "g")
static __device__ __forceinline__ s16x8 ldA(const unsigned short* __restrict__ WT,
                                            int K, int s, int kk, int lane){
  const unsigned short* p = WT + (size_t)((s<<4) + (lane&15))*K + (kk<<5) + ((lane>>4)<<2);
  ushort4 a = *(const ushort4*)p;
  ushort4 b = *(const ushort4*)(p + 16);
  s16x8 r;
  r[0]=(short)a.x; r[1]=(short)a.y; r[2]=(short)a.z; r[3]=(short)a.w;
  r[4]=(short)b.x; r[5]=(short)b.y; r[6]=(short)b.z; r[7]=(short)b.w;
  return r;
}
// B-fragment from an f32 feature row (already offset to the 32-wide chunk)
static __device__ __forceinline__ s16x8 ldBf32(const float* __restrict__ p, int q){
  float4 a = *(const float4*)(p + (q<<2));
  float4 b = *(const float4*)(p + 16 + (q<<2));
  s16x8 r;
  r[0]=(short)f2b(a.x); r[1]=(short)f2b(a.y); r[2]=(short)f2b(a.z); r[3]=(short)f2b(a.w);
  r[4]=(short)f2b(b.x); r[5]=(short)f2b(b.y); r[6]=(short)f2b(b.z); r[7]=(short)f2b(b.w);
  return r;
}

// ---------------- weight convert+transpose (f32 [K][128] -> bf16 [128][K]) ----
__global__ void k_conv(const float* __restrict__ W, unsigned short* __restrict__ WT, int kshift){
  const int K = 1 << kshift;
  const int idx = (blockIdx.x<<8) + threadIdx.x;
  if (idx < (K<<7)){
    const int n = idx >> kshift;
    const int k = idx & (K-1);
    WT[idx] = f2b(W[(size_t)k*HDIM + n]);
  }
}

// ---------------- CSR build ----------------
__global__ void k_degree(const int* __restrict__ coli, int* __restrict__ degi){
  const int e = (blockIdx.x<<8) + threadIdx.x;
  if (e < N_EDGES) atomicAdd(&degi[coli[e]], 1);
}
__global__ void k_scanA(const int* __restrict__ degi, int* __restrict__ off, int* __restrict__ bsum){
  const int t = threadIdx.x, b = blockIdx.x;
  const int i = (b<<8) + t;
  const int v = (i < N_NODES) ? degi[i] : 0;
  int x = v;
  const int lane = t & 63;
  #pragma unroll
  for (int d=1; d<64; d<<=1){ int y = __shfl_up(x, d); if (lane >= d) x += y; }
  __shared__ int wsum[4];
  if (lane == 63) wsum[t>>6] = x;
  __syncthreads();
  int wo = 0;
  #pragma unroll
  for (int w=0; w<4; ++w) if (w < (t>>6)) wo += wsum[w];
  const int incl = x + wo;
  if (i < N_NODES) off[i] = incl - v;
  if (t == 255) bsum[b] = incl;
}
__global__ void k_scanB(int* __restrict__ bsum, int nb){
  const int t = threadIdx.x;
  const int v = (t < nb) ? bsum[t] : 0;
  int x = v;
  const int lane = t & 63;
  #pragma unroll
  for (int d=1; d<64; d<<=1){ int y = __shfl_up(x, d); if (lane >= d) x += y; }
  __shared__ int wsum[4];
  if (lane == 63) wsum[t>>6] = x;
  __syncthreads();
  int wo = 0;
  #pragma unroll
  for (int w=0; w<4; ++w) if (w < (t>>6)) wo += wsum[w];
  const int incl = x + wo;
  if (t < nb) bsum[t] = incl - v;
}
__global__ void k_scanC(int* __restrict__ off, const int* __restrict__ bsum, int* __restrict__ cursor){
  const int i = (blockIdx.x<<8) + threadIdx.x;
  if (i < N_NODES){
    const int o = off[i] + bsum[i>>8];
    off[i] = o;
    cursor[i] = o;
  }
}
__global__ void k_fill(const int* __restrict__ coli, int* __restrict__ cursor, int* __restrict__ elist){
  const int e = (blockIdx.x<<8) + threadIdx.x;
  if (e < N_EDGES){
    const int p = atomicAdd(&cursor[coli[e]], 1);
    elist[p] = e;
  }
}
__global__ void k_xcopy(const float* __restrict__ xin, float* __restrict__ xbuf){
  const int i = (blockIdx.x<<8) + threadIdx.x;
  if (i < N_NODES*3) xbuf[i] = xin[i];
}

// ---------------- embedding: h = h_in @ W_emb + b_emb ----------------
__global__ __launch_bounds__(256) void k_embed(
    const float* __restrict__ hin, const unsigned short* __restrict__ WembT,
    const float* __restrict__ bemb, float* __restrict__ hbuf)
{
  __shared__ float s_b[128];
  const int tid = threadIdx.x;
  if (tid < 128) s_b[tid] = bemb[tid];
  __syncthreads();
  const int lane = tid & 63, q = lane>>4;
  const int n = (blockIdx.x<<6) + ((tid>>6)<<4) + (lane&15);
  const bool valid = n < N_NODES;
  const int nc = valid ? n : (N_NODES-1);
  const float* __restrict__ hp = hin + (size_t)nc*64;
  f32x4 acc[8];
  #pragma unroll
  for (int s=0;s<8;++s)
    #pragma unroll
    for (int r=0;r<4;++r) acc[s][r] = s_b[(s<<4)+(q<<2)+r];
  #pragma unroll
  for (int kk=0;kk<2;++kk){
    const s16x8 bf = ldBf32(hp + (kk<<5), q);
    #pragma unroll
    for (int s=0;s<8;++s) acc[s] = MFMA(ldA(WembT, 64, s, kk, lane), bf, acc[s]);
  }
  if (valid){
    float* op = hbuf + (size_t)n*HDIM;
    #pragma unroll
    for (int s=0;s<8;++s){
      float4 o; o.x=acc[s][0]; o.y=acc[s][1]; o.z=acc[s][2]; o.w=acc[s][3];
      *(float4*)(op + (s<<4) + (q<<2)) = o;
    }
  }
}

// ---------------- per-layer edge MLP (message + coord paths) ----------------
template<bool CSR>
__global__ __launch_bounds__(256) void k_edge_mlp(
    const float* __restrict__ hbuf, const float* __restrict__ xbuf,
    const int* __restrict__ rowi, const int* __restrict__ coli,
    const unsigned short* __restrict__ Wm1T, const float* __restrict__ bm1v,
    const float* __restrict__ wm1r256,
    const unsigned short* __restrict__ Wm2T, const float* __restrict__ bm2v,
    const unsigned short* __restrict__ Wc1T, const float* __restrict__ bc1v,
    const float* __restrict__ wc2v,
    unsigned short* __restrict__ m_buf, float* __restrict__ agg,
    float* __restrict__ cu)
{
  __shared__ int s_row[64], s_col[64];
  __shared__ float s_dist[64];
  __shared__ float s_rdir[64][3];
  __shared__ float s_bm1[128], s_w256[128], s_bm2[128], s_bc1[128], s_wc2[128];

  const int tid = threadIdx.x;
  const int ebase = blockIdx.x << 6;
  if (tid < 64){
    const int e = ebase + tid;
    const int r = rowi[e], c = coli[e];
    s_row[tid] = r; s_col[tid] = c;
    const float dx = xbuf[3*r+0] - xbuf[3*c+0];
    const float dy = xbuf[3*r+1] - xbuf[3*c+1];
    const float dz = xbuf[3*r+2] - xbuf[3*c+2];
    const float d = sqrtf(dx*dx + dy*dy + dz*dz);
    s_dist[tid] = d;
    const float inv = 1.0f / (d + 1e-8f);
    s_rdir[tid][0] = dx*inv; s_rdir[tid][1] = dy*inv; s_rdir[tid][2] = dz*inv;
  } else if (tid >= 128){
    const int f = tid - 128;
    s_bm1[f] = bm1v[f]; s_w256[f] = wm1r256[f]; s_bm2[f] = bm2v[f];
    s_bc1[f] = bc1v[f]; s_wc2[f] = wc2v[f];
  }
  __syncthreads();

  const int lane = tid & 63;
  const int q = lane >> 4;
  const int el = ((tid >> 6) << 4) + (lane & 15);
  const int eg = ebase + el;
  const float* __restrict__ hrow = hbuf + (size_t)s_row[el]*HDIM;
  const float* __restrict__ hcol = hbuf + (size_t)s_col[el]*HDIM;
  const float dist = s_dist[el];

  // GEMM1: [h_row | h_col] (K=256) @ Wm1 ; dist row folded into acc init
  f32x4 acc[8];
  #pragma unroll
  for (int s=0;s<8;++s)
    #pragma unroll
    for (int r=0;r<4;++r){
      const int f = (s<<4)+(q<<2)+r;
      acc[s][r] = s_bm1[f] + dist * s_w256[f];
    }
  #pragma unroll
  for (int kk=0;kk<8;++kk){
    const float* src = (kk < 4) ? (hrow + (kk<<5)) : (hcol + ((kk-4)<<5));
    const s16x8 bf = ldBf32(src, q);
    #pragma unroll
    for (int s=0;s<8;++s) acc[s] = MFMA(ldA(Wm1T, 256, s, kk, lane), bf, acc[s]);
  }
  // silu -> B-frags (C layout == next B layout; pure in-register chain)
  s16x8 sb[4];
  #pragma unroll
  for (int t=0;t<4;++t)
    #pragma unroll
    for (int j=0;j<8;++j)
      sb[t][j] = (short)f2b(silu_f(acc[(t<<1)+(j>>2)][j&3]));

  // GEMM2: @ Wm2
  f32x4 acc2[8];
  #pragma unroll
  for (int s=0;s<8;++s)
    #pragma unroll
    for (int r=0;r<4;++r) acc2[s][r] = s_bm2[(s<<4)+(q<<2)+r];
  #pragma unroll
  for (int kk=0;kk<4;++kk){
    #pragma unroll
    for (int s=0;s<8;++s) acc2[s] = MFMA(ldA(Wm2T, 128, s, kk, lane), sb[kk], acc2[s]);
  }
  s16x8 mb[4];  // m = silu(...) as bf16
  #pragma unroll
  for (int t=0;t<4;++t)
    #pragma unroll
    for (int j=0;j<8;++j)
      mb[t][j] = (short)f2b(silu_f(acc2[(t<<1)+(j>>2)][j&3]));

  if (CSR){
    unsigned short* mp = m_buf + (size_t)eg*HDIM + (q<<2);
    #pragma unroll
    for (int t=0;t<4;++t){
      ushort4 lo, hi;
      lo.x=(unsigned short)mb[t][0]; lo.y=(unsigned short)mb[t][1];
      lo.z=(unsigned short)mb[t][2]; lo.w=(unsigned short)mb[t][3];
      hi.x=(unsigned short)mb[t][4]; hi.y=(unsigned short)mb[t][5];
      hi.z=(unsigned short)mb[t][6]; hi.w=(unsigned short)mb[t][7];
      *(ushort4*)(mp + ((t<<1)<<4)) = lo;
      *(ushort4*)(mp + (((t<<1)+1)<<4)) = hi;
    }
  } else {
    float* ap = agg + (size_t)s_col[el]*HDIM + (q<<2);
    #pragma unroll
    for (int t=0;t<4;++t)
      #pragma unroll
      for (int j=0;j<8;++j)
        atomicAdd(ap + (((t<<1)+(j>>2))<<4) + (j&3), b2f((unsigned short)mb[t][j]));
  }

  // coord path: tanh(silu(m@Wc1+bc1)@Wc2) * rel_dir -> scatter
  f32x4 acc3[8];
  #pragma unroll
  for (int s=0;s<8;++s)
    #pragma unroll
    for (int r=0;r<4;++r) acc3[s][r] = s_bc1[(s<<4)+(q<<2)+r];
  #pragma unroll
  for (int kk=0;kk<4;++kk){
    #pragma unroll
    for (int s=0;s<8;++s) acc3[s] = MFMA(ldA(Wc1T, 128, s, kk, lane), mb[kk], acc3[s]);
  }
  float dot = 0.f;
  #pragma unroll
  for (int s=0;s<8;++s)
    #pragma unroll
    for (int r=0;r<4;++r)
      dot += silu_f(acc3[s][r]) * s_wc2[(s<<4)+(q<<2)+r];
  dot += __shfl_xor(dot, 16);
  dot += __shfl_xor(dot, 32);
  const float cm = tanhf(dot);
  if (q < 3)
    atomicAdd(&cu[(size_t)s_col[el]*3 + q], cm * s_rdir[el][q]);
}

// ---------------- per-layer node update ----------------
template<bool CSR>
__global__ __launch_bounds__(256) void k_node_mlp(
    float* __restrict__ hbuf, float* __restrict__ xbuf,
    const unsigned short* __restrict__ m_buf, const float* __restrict__ agg,
    const int* __restrict__ off, const int* __restrict__ degi, const int* __restrict__ elist,
    const float* __restrict__ cu,
    const unsigned short* __restrict__ Wn1T, const float* __restrict__ bn1v,
    const unsigned short* __restrict__ Wn2T, const float* __restrict__ bn2v,
    const float* __restrict__ lng, const float* __restrict__ lnb)
{
  __shared__ float s_bn1[128], s_bn2[128], s_g[128], s_b[128];
  const int tid = threadIdx.x;
  const int nbase = blockIdx.x << 6;
  if (tid >= 128){
    const int f = tid - 128;
    s_bn1[f]=bn1v[f]; s_bn2[f]=bn2v[f]; s_g[f]=lng[f]; s_b[f]=lnb[f];
  } else if (tid < 64){
    const int n = nbase + tid;
    if (n < N_NODES){
      const float dd = (float)degi[n] + 1.0f;
      #pragma unroll
      for (int c=0;c<3;++c) xbuf[3*n+c] += cu[3*n+c] / dd;
    }
  }
  __syncthreads();

  const int lane = tid & 63, q = lane >> 4;
  const int n = nbase + ((tid>>6)<<4) + (lane & 15);
  const bool valid = (n < N_NODES);
  const int nc = valid ? n : (N_NODES-1);
  const float* __restrict__ hp = hbuf + (size_t)nc*HDIM;

  // agg (segment-sum of m) accumulated directly in B-fragment slot layout
  float aggv[4][8];
  #pragma unroll
  for (int kk=0;kk<4;++kk)
    #pragma unroll
    for (int j=0;j<8;++j) aggv[kk][j]=0.f;
  if (CSR){
    const int st = off[nc];
    const int cnt = degi[nc];
    for (int ii=0; ii<cnt; ++ii){
      const unsigned short* mrow = m_buf + (size_t)elist[st+ii]*HDIM;
      #pragma unroll
      for (int kk=0;kk<4;++kk){
        ushort4 a = *(const ushort4*)(mrow + (kk<<5) + (q<<2));
        ushort4 b = *(const ushort4*)(mrow + (kk<<5) + 16 + (q<<2));
        aggv[kk][0]+=b2f(a.x); aggv[kk][1]+=b2f(a.y); aggv[kk][2]+=b2f(a.z); aggv[kk][3]+=b2f(a.w);
        aggv[kk][4]+=b2f(b.x); aggv[kk][5]+=b2f(b.y); aggv[kk][6]+=b2f(b.z); aggv[kk][7]+=b2f(b.w);
      }
    }
  } else {
    const float* ap = agg + (size_t)nc*HDIM;
    #pragma unroll
    for (int kk=0;kk<4;++kk){
      float4 a = *(const float4*)(ap + (kk<<5) + (q<<2));
      float4 b = *(const float4*)(ap + (kk<<5) + 16 + (q<<2));
      aggv[kk][0]=a.x; aggv[kk][1]=a.y; aggv[kk][2]=a.z; aggv[kk][3]=a.w;
      aggv[kk][4]=b.x; aggv[kk][5]=b.y; aggv[kk][6]=b.z; aggv[kk][7]=b.w;
    }
  }

  // GEMM1: [h | agg] (K=256) @ Wn1
  f32x4 acc[8];
  #pragma unroll
  for (int s=0;s<8;++s)
    #pragma unroll
    for (int r=0;r<4;++r) acc[s][r] = s_bn1[(s<<4)+(q<<2)+r];
  #pragma unroll
  for (int kk=0;kk<4;++kk){
    const s16x8 bf = ldBf32(hp + (kk<<5), q);
    #pragma unroll
    for (int s=0;s<8;++s) acc[s] = MFMA(ldA(Wn1T, 256, s, kk, lane), bf, acc[s]);
  }
  #pragma unroll
  for (int kk=0;kk<4;++kk){
    s16x8 bf;
    #pragma unroll
    for (int j=0;j<8;++j) bf[j] = (short)f2b(aggv[kk][j]);
    #pragma unroll
    for (int s=0;s<8;++s) acc[s] = MFMA(ldA(Wn1T, 256, s, kk+4, lane), bf, acc[s]);
  }
  s16x8 sb[4];
  #pragma unroll
  for (int t=0;t<4;++t)
    #pragma unroll
    for (int j=0;j<8;++j)
      sb[t][j] = (short)f2b(silu_f(acc[(t<<1)+(j>>2)][j&3]));
  f32x4 acc2[8];
  #pragma unroll
  for (int s=0;s<8;++s)
    #pragma unroll
    for (int r=0;r<4;++r) acc2[s][r] = s_bn2[(s<<4)+(q<<2)+r];
  #pragma unroll
  for (int kk=0;kk<4;++kk){
    #pragma unroll
    for (int s=0;s<8;++s) acc2[s] = MFMA(ldA(Wn2T, 128, s, kk, lane), sb[kk], acc2[s]);
  }

  // residual + LayerNorm
  float v[8][4];
  float sum = 0.f;
  #pragma unroll
  for (int s=0;s<8;++s){
    float4 h4 = *(const float4*)(hp + (s<<4) + (q<<2));
    v[s][0] = h4.x + acc2[s][0]; v[s][1] = h4.y + acc2[s][1];
    v[s][2] = h4.z + acc2[s][2]; v[s][3] = h4.w + acc2[s][3];
    sum += v[s][0]+v[s][1]+v[s][2]+v[s][3];
  }
  sum += __shfl_xor(sum, 16);
  sum += __shfl_xor(sum, 32);
  const float mu = sum * (1.0f/128.0f);
  float vs = 0.f;
  #pragma unroll
  for (int s=0;s<8;++s)
    #pragma unroll
    for (int r=0;r<4;++r){ const float d = v[s][r]-mu; vs += d*d; }
  vs += __shfl_xor(vs, 16);
  vs += __shfl_xor(vs, 32);
  const float rs = rsqrtf(vs*(1.0f/128.0f) + 1e-5f);
  if (valid){
    float* op = hbuf + (size_t)n*HDIM;
    #pragma unroll
    for (int s=0;s<8;++s){
      const int f0 = (s<<4)+(q<<2);
      float4 o;
      o.x = (v[s][0]-mu)*rs*s_g[f0+0] + s_b[f0+0];
      o.y = (v[s][1]-mu)*rs*s_g[f0+1] + s_b[f0+1];
      o.z = (v[s][2]-mu)*rs*s_g[f0+2] + s_b[f0+2];
      o.w = (v[s][3]-mu)*rs*s_g[f0+3] + s_b[f0+3];
      *(float4*)(op + f0) = o;
    }
  }
}

// ---------------- epsilon head: edge part ----------------
__global__ __launch_bounds__(256) void k_eps_edge(
    const float* __restrict__ hbuf, const float* __restrict__ xbuf,
    const int* __restrict__ rowi, const int* __restrict__ coli,
    const unsigned short* __restrict__ WemT, const float* __restrict__ bem1v,
    const float* __restrict__ wem_rows,
    const unsigned short* __restrict__ Wem2T, const float* __restrict__ bem2v,
    const unsigned short* __restrict__ Wec1T, const float* __restrict__ bec1v,
    const float* __restrict__ Wec2, const float* __restrict__ bec2,
    float* __restrict__ epsb)
{
  __shared__ int s_row[64], s_col[64];
  __shared__ float s_rel[64][3], s_dist[64];
  __shared__ float s_bem1[128], s_w4[4][128], s_bem2[128], s_bec1[128], s_wc[3][128];
  const int tid = threadIdx.x;
  const int ebase = blockIdx.x << 6;
  if (tid < 64){
    const int e = ebase + tid;
    const int r = rowi[e], c = coli[e];
    s_row[tid]=r; s_col[tid]=c;
    const float dx = xbuf[3*r+0]-xbuf[3*c+0];
    const float dy = xbuf[3*r+1]-xbuf[3*c+1];
    const float dz = xbuf[3*r+2]-xbuf[3*c+2];
    s_rel[tid][0]=dx; s_rel[tid][1]=dy; s_rel[tid][2]=dz;
    s_dist[tid] = sqrtf(dx*dx+dy*dy+dz*dz);
  } else if (tid >= 128){
    const int f = tid - 128;
    s_bem1[f]=bem1v[f];
    s_w4[0][f]=wem_rows[f];     s_w4[1][f]=wem_rows[128+f];
    s_w4[2][f]=wem_rows[256+f]; s_w4[3][f]=wem_rows[384+f];
    s_bem2[f]=bem2v[f]; s_bec1[f]=bec1v[f];
    s_wc[0][f]=Wec2[f*3+0]; s_wc[1][f]=Wec2[f*3+1]; s_wc[2][f]=Wec2[f*3+2];
  }
  __syncthreads();
  const int lane = tid & 63, q = lane >> 4;
  const int el = ((tid>>6)<<4) + (lane & 15);
  const float* __restrict__ hrow = hbuf + (size_t)s_row[el]*HDIM;
  const float* __restrict__ hcol = hbuf + (size_t)s_col[el]*HDIM;

  f32x4 acc[8];
  #pragma unroll
  for (int s=0;s<8;++s)
    #pragma unroll
    for (int r=0;r<4;++r){
      const int f = (s<<4)+(q<<2)+r;
      acc[s][r] = s_bem1[f] + s_rel[el][0]*s_w4[0][f] + s_rel[el][1]*s_w4[1][f]
                + s_rel[el][2]*s_w4[2][f] + s_dist[el]*s_w4[3][f];
    }
  #pragma unroll
  for (int kk=0;kk<8;++kk){
    const float* src = (kk < 4) ? (hrow + (kk<<5)) : (hcol + ((kk-4)<<5));
    const s16x8 bf = ldBf32(src, q);
    #pragma unroll
    for (int s=0;s<8;++s) acc[s] = MFMA(ldA(WemT, 256, s, kk, lane), bf, acc[s]);
  }
  s16x8 sb[4];
  #pragma unroll
  for (int t=0;t<4;++t)
    #pragma unroll
    for (int j=0;j<8;++j)
      sb[t][j] = (short)f2b(silu_f(acc[(t<<1)+(j>>2)][j&3]));
  f32x4 acc2[8];
  #pragma unroll
  for (int s=0;s<8;++s)
    #pragma unroll
    for (int r=0;r<4;++r) acc2[s][r] = s_bem2[(s<<4)+(q<<2)+r];
  #pragma unroll
  for (int kk=0;kk<4;++kk){
    #pragma unroll
    for (int s=0;s<8;++s) acc2[s] = MFMA(ldA(Wem2T, 128, s, kk, lane), sb[kk], acc2[s]);
  }
  s16x8 mb[4];
  #pragma unroll
  for (int t=0;t<4;++t)
    #pragma unroll
    for (int j=0;j<8;++j)
      mb[t][j] = (short)f2b(silu_f(acc2[(t<<1)+(j>>2)][j&3]));
  f32x4 acc3[8];
  #pragma unroll
  for (int s=0;s<8;++s)
    #pragma unroll
    for (int r=0;r<4;++r) acc3[s][r] = s_bec1[(s<<4)+(q<<2)+r];
  #pragma unroll
  for (int kk=0;kk<4;++kk){
    #pragma unroll
    for (int s=0;s<8;++s) acc3[s] = MFMA(ldA(Wec1T, 128, s, kk, lane), mb[kk], acc3[s]);
  }
  float d0=0.f, d1=0.f, d2=0.f;
  #pragma unroll
  for (int s=0;s<8;++s)
    #pragma unroll
    for (int r=0;r<4;++r){
      const int f = (s<<4)+(q<<2)+r;
      const float ev = silu_f(acc3[s][r]);
      d0 += ev*s_wc[0][f]; d1 += ev*s_wc[1][f]; d2 += ev*s_wc[2][f];
    }
  d0 += __shfl_xor(d0,16); d0 += __shfl_xor(d0,32);
  d1 += __shfl_xor(d1,16); d1 += __shfl_xor(d1,32);
  d2 += __shfl_xor(d2,16); d2 += __shfl_xor(d2,32);
  if (q < 3){
    const float val = (q==0)?d0:((q==1)?d1:d2);
    atomicAdd(&epsb[(size_t)s_col[el]*3 + q], val + bec2[q]);
  }
}

// ---------------- epsilon head: node part ----------------
__global__ __launch_bounds__(256) void k_eps_node(
    const float* __restrict__ hbuf, const float* __restrict__ xbuf,
    const unsigned short* __restrict__ Wh1T, const float* __restrict__ bh1v,
    const float* __restrict__ wh1_rows,
    const float* __restrict__ Wh2, const float* __restrict__ bh2,
    float* __restrict__ epsb)
{
  __shared__ float s_bh1[128], s_w3[3][128], s_wc[3][128];
  const int tid = threadIdx.x;
  if (tid >= 128){
    const int f = tid - 128;
    s_bh1[f]=bh1v[f];
    s_w3[0][f]=wh1_rows[f]; s_w3[1][f]=wh1_rows[128+f]; s_w3[2][f]=wh1_rows[256+f];
    s_wc[0][f]=Wh2[f*3+0]; s_wc[1][f]=Wh2[f*3+1]; s_wc[2][f]=Wh2[f*3+2];
  }
  __syncthreads();
  const int lane = tid & 63, q = lane >> 4;
  const int n = (blockIdx.x<<6) + ((tid>>6)<<4) + (lane & 15);
  const bool valid = n < N_NODES;
  const int nc = valid ? n : (N_NODES-1);
  const float* __restrict__ hp = hbuf + (size_t)nc*HDIM;
  const float x0 = xbuf[3*nc+0], x1 = xbuf[3*nc+1], x2 = xbuf[3*nc+2];
  f32x4 acc[8];
  #pragma unroll
  for (int s=0;s<8;++s)
    #pragma unroll
    for (int r=0;r<4;++r){
      const int f = (s<<4)+(q<<2)+r;
      acc[s][r] = s_bh1[f] + x0*s_w3[0][f] + x1*s_w3[1][f] + x2*s_w3[2][f];
    }
  #pragma unroll
  for (int kk=0;kk<4;++kk){
    const s16x8 bf = ldBf32(hp + (kk<<5), q);
    #pragma unroll
    for (int s=0;s<8;++s) acc[s] = MFMA(ldA(Wh1T, 128, s, kk, lane), bf, acc[s]);
  }
  float d0=0.f, d1=0.f, d2=0.f;
  #pragma unroll
  for (int s=0;s<8;++s)
    #pragma unroll
    for (int r=0;r<4;++r){
      const int f = (s<<4)+(q<<2)+r;
      const float ev = silu_f(acc[s][r]);
      d0 += ev*s_wc[0][f]; d1 += ev*s_wc[1][f]; d2 += ev*s_wc[2][f];
    }
  d0 += __shfl_xor(d0,16); d0 += __shfl_xor(d0,32);
  d1 += __shfl_xor(d1,16); d1 += __shfl_xor(d1,32);
  d2 += __shfl_xor(d2,16); d2 += __shfl_xor(d2,32);
  if (valid && q < 3){
    const float val = (q==0)?d0:((q==1)?d1:d2);
    epsb[(size_t)n*3 + q] += val + bh2[q];
  }
}

extern "C" void kernel_launch(void* const* d_in, const int* in_sizes, int n_in,
                              void* d_out, int out_size, void* d_ws, size_t ws_size,
                              hipStream_t stream)
{
  (void)in_sizes; (void)n_in; (void)out_size;
  const float* h_in  = (const float*)d_in[0];
  const float* x_in  = (const float*)d_in[1];
  const int*   eidx  = (const int*)d_in[2];
  const float* W_emb = (const float*)d_in[3];
  const float* b_emb = (const float*)d_in[4];
  const float* Wm1 = (const float*)d_in[5];
  const float* bm1 = (const float*)d_in[6];
  const float* Wm2 = (const float*)d_in[7];
  const float* bm2 = (const float*)d_in[8];
  const float* Wc1 = (const float*)d_in[9];
  const float* bc1 = (const float*)d_in[10];
  const float* Wc2 = (const float*)d_in[11];
  const float* Wn1 = (const float*)d_in[12];
  const float* bn1 = (const float*)d_in[13];
  const float* Wn2 = (const float*)d_in[14];
  const float* bn2 = (const float*)d_in[15];
  const float* lng = (const float*)d_in[16];
  const float* lnb = (const float*)d_in[17];
  const float* Wem1 = (const float*)d_in[18];
  const float* bem1 = (const float*)d_in[19];
  const float* Wem2 = (const float*)d_in[20];
  const float* bem2 = (const float*)d_in[21];
  const float* Wec1 = (const float*)d_in[22];
  const float* bec1 = (const float*)d_in[23];
  const float* Wec2 = (const float*)d_in[24];
  const float* bec2 = (const float*)d_in[25];
  const float* Wh1 = (const float*)d_in[26];
  const float* bh1 = (const float*)d_in[27];
  const float* Wh2 = (const float*)d_in[28];
  const float* bh2 = (const float*)d_in[29];

  const int* rowi = eidx;
  const int* coli = eidx + N_EDGES;

  float* hbuf = (float*)d_out;
  float* xbuf = hbuf + (size_t)N_NODES*HDIM;
  float* epsb = xbuf + (size_t)N_NODES*3;

  char* wp = (char*)d_ws;
  auto alloc = [&](size_t bytes)->char*{
    char* p = wp; wp += (bytes + 255) & ~(size_t)255; return p;
  };
  unsigned short* WembT = (unsigned short*)alloc((size_t)128*64*2);
  unsigned short *Wm1T[NLAYERS], *Wm2T[NLAYERS], *Wc1T[NLAYERS], *Wn1T[NLAYERS], *Wn2T[NLAYERS];
  for (int i=0;i<NLAYERS;++i){
    Wm1T[i] = (unsigned short*)alloc((size_t)128*256*2);
    Wm2T[i] = (unsigned short*)alloc((size_t)128*128*2);
    Wc1T[i] = (unsigned short*)alloc((size_t)128*128*2);
    Wn1T[i] = (unsigned short*)alloc((size_t)128*256*2);
    Wn2T[i] = (unsigned short*)alloc((size_t)128*128*2);
  }
  unsigned short* WemT  = (unsigned short*)alloc((size_t)128*256*2);
  unsigned short* Wem2T = (unsigned short*)alloc((size_t)128*128*2);
  unsigned short* Wec1T = (unsigned short*)alloc((size_t)128*128*2);
  unsigned short* Wh1T  = (unsigned short*)alloc((size_t)128*128*2);
  int* degi   = (int*)alloc((size_t)N_NODES*4);
  int* offv   = (int*)alloc((size_t)N_NODES*4);
  int* cursor = (int*)alloc((size_t)N_NODES*4);
  int* bsum   = (int*)alloc(4096);
  float* cu   = (float*)alloc((size_t)N_NODES*3*4);
  int* elist  = (int*)alloc((size_t)N_EDGES*4);
  char* big   = alloc((size_t)N_EDGES*HDIM*2);       // m_buf (CSR) or agg (atomic)
  const bool use_csr = ((size_t)(wp - (char*)d_ws) <= ws_size);
  unsigned short* m_buf = (unsigned short*)big;
  float* agg = (float*)big;

  // convert+transpose weights to bf16 [out][in]
  auto conv = [&](const float* W, unsigned short* WT, int kshift){
    const int tot = 128 << kshift;
    k_conv<<<dim3((tot+255)/256), dim3(256), 0, stream>>>(W, WT, kshift);
  };
  conv(W_emb, WembT, 6);
  for (int i=0;i<NLAYERS;++i){
    conv(Wm1 + (size_t)i*257*128, Wm1T[i], 8);
    conv(Wm2 + (size_t)i*128*128, Wm2T[i], 7);
    conv(Wc1 + (size_t)i*128*128, Wc1T[i], 7);
    conv(Wn1 + (size_t)i*256*128, Wn1T[i], 8);
    conv(Wn2 + (size_t)i*128*128, Wn2T[i], 7);
  }
  conv(Wem1, WemT, 8);
  conv(Wem2, Wem2T, 7);
  conv(Wec1, Wec1T, 7);
  conv(Wh1,  Wh1T,  7);

  hipMemsetAsync(degi, 0, (size_t)N_NODES*4, stream);
  k_degree<<<dim3((N_EDGES+255)/256), dim3(256), 0, stream>>>(coli, degi);
  const int nb = (N_NODES + 255)/256;
  if (use_csr){
    k_scanA<<<dim3(nb), dim3(256), 0, stream>>>(degi, offv, bsum);
    k_scanB<<<dim3(1), dim3(256), 0, stream>>>(bsum, nb);
    k_scanC<<<dim3(nb), dim3(256), 0, stream>>>(offv, bsum, cursor);
    k_fill<<<dim3((N_EDGES+255)/256), dim3(256), 0, stream>>>(coli, cursor, elist);
  }
  k_xcopy<<<dim3((N_NODES*3+255)/256), dim3(256), 0, stream>>>(x_in, xbuf);
  k_embed<<<dim3((N_NODES+63)/64), dim3(256), 0, stream>>>(h_in, WembT, b_emb, hbuf);

  for (int i=0;i<NLAYERS;++i){
    hipMemsetAsync(cu, 0, (size_t)N_NODES*3*4, stream);
    if (!use_csr) hipMemsetAsync(agg, 0, (size_t)N_NODES*HDIM*4, stream);
    const float* wm1r256 = Wm1 + (size_t)i*257*128 + (size_t)256*128;
    if (use_csr){
      k_edge_mlp<true><<<dim3(N_EDGES/64), dim3(256), 0, stream>>>(
        hbuf, xbuf, rowi, coli,
        Wm1T[i], bm1 + i*128, wm1r256,
        Wm2T[i], bm2 + i*128,
        Wc1T[i], bc1 + i*128, Wc2 + i*128,
        m_buf, agg, cu);
      k_node_mlp<true><<<dim3((N_NODES+63)/64), dim3(256), 0, stream>>>(
        hbuf, xbuf, m_buf, agg, offv, degi, elist, cu,
        Wn1T[i], bn1 + i*128, Wn2T[i], bn2 + i*128, lng + i*128, lnb + i*128);
    } else {
      k_edge_mlp<false><<<dim3(N_EDGES/64), dim3(256), 0, stream>>>(
        hbuf, xbuf, rowi, coli,
        Wm1T[i], bm1 + i*128, wm1r256,
        Wm2T[i], bm2 + i*128,
        Wc1T[i], bc1 + i*128, Wc2 + i*128,
        m_buf, agg, cu);
      k_node_mlp<false><<<dim3((N_NODES+63)/64), dim3(256), 0, stream>>>(
        hbuf, xbuf, m_buf, agg, offv, degi, elist, cu,
        Wn1T[i], bn1 + i*128, Wn2T[i], bn2 + i*128, lng + i*128, lnb + i*128);
    }
  }
  hipMemsetAsync(epsb, 0, (size_t)N_NODES*3*4, stream);
  k_eps_edge<<<dim3(N_EDGES/64), dim3(256), 0, stream>>>(
    hbuf, xbuf, rowi, coli,
    WemT, bem1, Wem1 + (size_t)256*128,
    Wem2T, bem2, Wec1T, bec1, Wec2, bec2, epsb);
  k_eps_node<<<dim3((N_NODES+63)/64), dim3(256), 0, stream>>>(
    hbuf, xbuf, Wh1T, bh1, Wh1 + (size_t)128*128, Wh2, bh2, epsb);
}

// Round 2
// 1382.352 us; speedup vs baseline: 3.9368x; 3.9368x over previous
//
#include <hip/hip_runtime.h>

#define N_NODES 50000
#define N_EDGES 640000
#define HDIM    128
#define NLAYERS 3

typedef __attribute__((ext_vector_type(4))) float f32x4;
typedef short s16x8 __attribute__((ext_vector_type(8)));
typedef __bf16 bf16v8 __attribute__((ext_vector_type(8)));

static __device__ __forceinline__ unsigned short f2b(float f){
  unsigned int u = __float_as_uint(f);
  unsigned int r = u + 0x7FFFu + ((u >> 16) & 1u);
  return (unsigned short)(r >> 16);
}
static __device__ __forceinline__ float b2f(unsigned short h){
  return __uint_as_float(((unsigned int)h) << 16);
}
static __device__ __forceinline__ float silu_f(float x){
  return x / (1.0f + __expf(-x));
}
static __device__ __forceinline__ f32x4 MFMA(s16x8 a, s16x8 b, f32x4 c){
  return __builtin_amdgcn_mfma_f32_16x16x32_bf16(
      __builtin_bit_cast(bf16v8, a), __builtin_bit_cast(bf16v8, b), c, 0, 0, 0);
}

// old-style A-fragment from global (node/embed kernels): WT[out][K] row-major
static __device__ __forceinline__ s16x8 ldA(const unsigned short* __restrict__ WT,
                                            int K, int s, int kk, int lane){
  const unsigned short* p = WT + (size_t)((s<<4) + (lane&15))*K + (kk<<5) + ((lane>>4)<<2);
  ushort4 a = *(const ushort4*)p;
  ushort4 b = *(const ushort4*)(p + 16);
  s16x8 r;
  r[0]=(short)a.x; r[1]=(short)a.y; r[2]=(short)a.z; r[3]=(short)a.w;
  r[4]=(short)b.x; r[5]=(short)b.y; r[6]=(short)b.z; r[7]=(short)b.w;
  return r;
}
// B-fragment from an f32 feature row
static __device__ __forceinline__ s16x8 ldBf32(const float* __restrict__ p, int q){
  float4 a = *(const float4*)(p + (q<<2));
  float4 b = *(const float4*)(p + 16 + (q<<2));
  s16x8 r;
  r[0]=(short)f2b(a.x); r[1]=(short)f2b(a.y); r[2]=(short)f2b(a.z); r[3]=(short)f2b(a.w);
  r[4]=(short)f2b(b.x); r[5]=(short)f2b(b.y); r[6]=(short)f2b(b.z); r[7]=(short)f2b(b.w);
  return r;
}

// stage tile T (8KB) of `blob` into sm.wbuf[T&1], 2KB per wave, linear copy.
#define STAGE(T) do { \
    const unsigned short* _src = blob + (((size_t)(T))<<12) + (w<<10) + (lane<<3); \
    unsigned char* _dst = &sm.wbuf[(T)&1][w<<11]; \
    __builtin_amdgcn_global_load_lds((const __attribute__((address_space(1))) void*)_src, \
        (__attribute__((address_space(3))) void*)_dst, 16, 0, 0); \
    __builtin_amdgcn_global_load_lds((const __attribute__((address_space(1))) void*)(_src+512), \
        (__attribute__((address_space(3))) void*)(_dst+1024), 16, 0, 0); \
  } while(0)
#define WAITV2 asm volatile("s_waitcnt vmcnt(2)" ::: "memory")
#define WAITV0 asm volatile("s_waitcnt vmcnt(0)" ::: "memory")
#define BARF do{ __builtin_amdgcn_s_barrier(); asm volatile("" ::: "memory"); }while(0)
#define EBAR do{ asm volatile("" ::: "memory"); __builtin_amdgcn_s_barrier(); }while(0)

// ---------------- weight convert+transpose (f32 [K][128] -> bf16 [128][K]) ----
__global__ void k_conv(const float* __restrict__ W, unsigned short* __restrict__ WT, int kshift){
  const int K = 1 << kshift;
  const int idx = (blockIdx.x<<8) + threadIdx.x;
  if (idx < (K<<7)){
    const int n = idx >> kshift;
    const int k = idx & (K-1);
    WT[idx] = f2b(W[(size_t)k*HDIM + n]);
  }
}

// blob layout: 16 tiles of 4096 bf16. tile t, elem i: n=(i>>5)&127, slot=(i>>3)&3,
// j=i&7; q=slot^((n>>1)&3); k_local=((j>>2)<<4)+(q<<2)+(j&3).
// tiles 0..7 -> W1 (K up to 256), 8..11 -> W2 (K=128), 12..15 -> W3 (K=128).
__global__ void k_conv_blob(const float* __restrict__ W1, const float* __restrict__ W2,
                            const float* __restrict__ W3, unsigned short* __restrict__ blob){
  const int i = (blockIdx.x<<8) + threadIdx.x;   // 65536 total
  const int t = i >> 12;
  const int n = (i >> 5) & 127;
  const int slot = (i >> 3) & 3;
  const int j = i & 7;
  const int q = slot ^ ((n >> 1) & 3);
  const int kl = ((j >> 2) << 4) + (q << 2) + (j & 3);
  const float* W; int k;
  if (t < 8){ W = W1; k = (t<<5) + kl; }
  else if (t < 12){ W = W2; k = ((t-8)<<5) + kl; }
  else { W = W3; k = ((t-12)<<5) + kl; }
  blob[i] = f2b(W[(size_t)k*HDIM + n]);
}

// ---------------- CSR build ----------------
__global__ void k_degree(const int* __restrict__ coli, int* __restrict__ degi){
  const int e = (blockIdx.x<<8) + threadIdx.x;
  if (e < N_EDGES) atomicAdd(&degi[coli[e]], 1);
}
__global__ void k_scanA(const int* __restrict__ degi, int* __restrict__ off, int* __restrict__ bsum){
  const int t = threadIdx.x, b = blockIdx.x;
  const int i = (b<<8) + t;
  const int v = (i < N_NODES) ? degi[i] : 0;
  int x = v;
  const int lane = t & 63;
  #pragma unroll
  for (int d=1; d<64; d<<=1){ int y = __shfl_up(x, d); if (lane >= d) x += y; }
  __shared__ int wsum[4];
  if (lane == 63) wsum[t>>6] = x;
  __syncthreads();
  int wo = 0;
  #pragma unroll
  for (int w=0; w<4; ++w) if (w < (t>>6)) wo += wsum[w];
  const int incl = x + wo;
  if (i < N_NODES) off[i] = incl - v;
  if (t == 255) bsum[b] = incl;
}
__global__ void k_scanB(int* __restrict__ bsum, int nb){
  const int t = threadIdx.x;
  const int v = (t < nb) ? bsum[t] : 0;
  int x = v;
  const int lane = t & 63;
  #pragma unroll
  for (int d=1; d<64; d<<=1){ int y = __shfl_up(x, d); if (lane >= d) x += y; }
  __shared__ int wsum[4];
  if (lane == 63) wsum[t>>6] = x;
  __syncthreads();
  int wo = 0;
  #pragma unroll
  for (int w=0; w<4; ++w) if (w < (t>>6)) wo += wsum[w];
  const int incl = x + wo;
  if (t < nb) bsum[t] = incl - v;
}
__global__ void k_scanC(int* __restrict__ off, const int* __restrict__ bsum, int* __restrict__ cursor){
  const int i = (blockIdx.x<<8) + threadIdx.x;
  if (i < N_NODES){
    const int o = off[i] + bsum[i>>8];
    off[i] = o;
    cursor[i] = o;
  }
}
__global__ void k_fill(const int* __restrict__ coli, int* __restrict__ cursor, int* __restrict__ elist){
  const int e = (blockIdx.x<<8) + threadIdx.x;
  if (e < N_EDGES){
    const int p = atomicAdd(&cursor[coli[e]], 1);
    elist[p] = e;
  }
}
__global__ void k_xcopy(const float* __restrict__ xin, float* __restrict__ xbuf){
  const int i = (blockIdx.x<<8) + threadIdx.x;
  if (i < N_NODES*3) xbuf[i] = xin[i];
}

// ---------------- embedding: h = h_in @ W_emb + b_emb (+ bf16 mirror) --------
__global__ __launch_bounds__(256) void k_embed(
    const float* __restrict__ hin, const unsigned short* __restrict__ WembT,
    const float* __restrict__ bemb, float* __restrict__ hbuf,
    unsigned short* __restrict__ hb)
{
  __shared__ float s_b[128];
  const int tid = threadIdx.x;
  if (tid < 128) s_b[tid] = bemb[tid];
  __syncthreads();
  const int lane = tid & 63, q = lane>>4;
  const int n = (blockIdx.x<<6) + ((tid>>6)<<4) + (lane&15);
  const bool valid = n < N_NODES;
  const int nc = valid ? n : (N_NODES-1);
  const float* __restrict__ hp = hin + (size_t)nc*64;
  f32x4 acc[8];
  #pragma unroll
  for (int s=0;s<8;++s)
    #pragma unroll
    for (int r=0;r<4;++r) acc[s][r] = s_b[(s<<4)+(q<<2)+r];
  #pragma unroll
  for (int kk=0;kk<2;++kk){
    const s16x8 bf = ldBf32(hp + (kk<<5), q);
    #pragma unroll
    for (int s=0;s<8;++s) acc[s] = MFMA(ldA(WembT, 64, s, kk, lane), bf, acc[s]);
  }
  if (valid){
    float* op = hbuf + (size_t)n*HDIM;
    unsigned short* hbw = hb + (size_t)n*HDIM;
    #pragma unroll
    for (int s=0;s<8;++s){
      float4 o; o.x=acc[s][0]; o.y=acc[s][1]; o.z=acc[s][2]; o.w=acc[s][3];
      *(float4*)(op + (s<<4) + (q<<2)) = o;
      ushort4 u; u.x=f2b(o.x); u.y=f2b(o.y); u.z=f2b(o.z); u.w=f2b(o.w);
      *(ushort4*)(hbw + ((s>>1)<<5) + (q<<3) + ((s&1)<<2)) = u;
    }
  }
}

// ---------------- per-layer edge MLP (LDS-staged weights, 128 edges/block) ----
template<bool CSR>
__global__ __launch_bounds__(256) void k_edge_mlp(
    const unsigned short* __restrict__ hb, const float* __restrict__ xbuf,
    const int* __restrict__ rowi, const int* __restrict__ coli,
    const unsigned short* __restrict__ blob,
    const float* __restrict__ bm1v, const float* __restrict__ wm1r256,
    const float* __restrict__ bm2v, const float* __restrict__ bc1v,
    const float* __restrict__ wc2v,
    unsigned short* __restrict__ m_buf, float* __restrict__ agg,
    float* __restrict__ cu)
{
  __shared__ struct {
    alignas(16) unsigned char wbuf[2][8192];
    int row[128]; int col[128];
    float dist[128]; float rdir[128][3];
    float b1[128], w256[128], b2[128], bc1[128], wc2[128];
  } sm;
  const int tid = threadIdx.x;
  const int ebase = blockIdx.x << 7;
  const int lane = tid & 63, w = tid >> 6, q = lane >> 4;
  if (tid < 128){
    const int e = ebase + tid;
    const int r = rowi[e], c = coli[e];
    sm.row[tid] = r; sm.col[tid] = c;
    const float dx = xbuf[3*r+0] - xbuf[3*c+0];
    const float dy = xbuf[3*r+1] - xbuf[3*c+1];
    const float dz = xbuf[3*r+2] - xbuf[3*c+2];
    const float d = sqrtf(dx*dx + dy*dy + dz*dz);
    sm.dist[tid] = d;
    const float inv = 1.0f / (d + 1e-8f);
    sm.rdir[tid][0] = dx*inv; sm.rdir[tid][1] = dy*inv; sm.rdir[tid][2] = dz*inv;
  } else {
    const int f = tid - 128;
    sm.b1[f] = bm1v[f]; sm.w256[f] = wm1r256[f]; sm.b2[f] = bm2v[f];
    sm.bc1[f] = bc1v[f]; sm.wc2[f] = wc2v[f];
  }
  STAGE(0);
  __syncthreads();

  const int toff = ((lane&15)<<6) + ((q ^ ((lane>>1)&3))<<4);
  const int q8 = q << 3;
  const int el0 = (w<<5) + (lane&15);
  const int el1 = el0 + 16;
  const unsigned short* __restrict__ hr0 = hb + (size_t)sm.row[el0]*HDIM;
  const unsigned short* __restrict__ hc0 = hb + (size_t)sm.col[el0]*HDIM;
  const unsigned short* __restrict__ hr1 = hb + (size_t)sm.row[el1]*HDIM;
  const unsigned short* __restrict__ hc1 = hb + (size_t)sm.col[el1]*HDIM;
  const float d0 = sm.dist[el0], d1 = sm.dist[el1];

  // GEMM1: [h_row | h_col] (K=256) @ Wm1 ; dist row folded into acc init
  f32x4 acc0[8], acc1[8];
  #pragma unroll
  for (int s=0;s<8;++s)
    #pragma unroll
    for (int r=0;r<4;++r){
      const int f = (s<<4)+(q<<2)+r;
      acc0[s][r] = sm.b1[f] + d0 * sm.w256[f];
      acc1[s][r] = sm.b1[f] + d1 * sm.w256[f];
    }
  s16x8 B0 = *(const s16x8*)(hr0 + q8);
  s16x8 B1 = *(const s16x8*)(hr1 + q8);
  #pragma unroll
  for (int t=0;t<8;++t){
    STAGE(t+1);
    WAITV2; BARF;
    s16x8 nB0, nB1;
    if (t < 7){
      const int kk = t+1;
      const int ho = ((kk&3)<<5) + q8;
      nB0 = *(const s16x8*)(((kk<4)?hr0:hc0) + ho);
      nB1 = *(const s16x8*)(((kk<4)?hr1:hc1) + ho);
    }
    #pragma unroll
    for (int s=0;s<8;++s){
      const s16x8 A = *(const s16x8*)(&sm.wbuf[t&1][(s<<10)+toff]);
      acc0[s] = MFMA(A, B0, acc0[s]);
      acc1[s] = MFMA(A, B1, acc1[s]);
    }
    EBAR;
    if (t < 7){ B0 = nB0; B1 = nB1; }
  }

  // silu -> B-frags (C layout == next B layout)
  s16x8 sb0[4], sb1[4];
  #pragma unroll
  for (int t=0;t<4;++t)
    #pragma unroll
    for (int j=0;j<8;++j){
      sb0[t][j] = (short)f2b(silu_f(acc0[(t<<1)+(j>>2)][j&3]));
      sb1[t][j] = (short)f2b(silu_f(acc1[(t<<1)+(j>>2)][j&3]));
    }

  // GEMM2: @ Wm2 (tiles 8..11)
  f32x4 acc20[8], acc21[8];
  #pragma unroll
  for (int s=0;s<8;++s)
    #pragma unroll
    for (int r=0;r<4;++r){
      const float b = sm.b2[(s<<4)+(q<<2)+r];
      acc20[s][r] = b; acc21[s][r] = b;
    }
  #pragma unroll
  for (int t=0;t<4;++t){
    STAGE(9+t);
    WAITV2; BARF;
    #pragma unroll
    for (int s=0;s<8;++s){
      const s16x8 A = *(const s16x8*)(&sm.wbuf[t&1][(s<<10)+toff]);
      acc20[s] = MFMA(A, sb0[t], acc20[s]);
      acc21[s] = MFMA(A, sb1[t], acc21[s]);
    }
    EBAR;
  }
  s16x8 mb0[4], mb1[4];
  #pragma unroll
  for (int t=0;t<4;++t)
    #pragma unroll
    for (int j=0;j<8;++j){
      mb0[t][j] = (short)f2b(silu_f(acc20[(t<<1)+(j>>2)][j&3]));
      mb1[t][j] = (short)f2b(silu_f(acc21[(t<<1)+(j>>2)][j&3]));
    }

  // GEMM3: coord path @ Wc1 (tiles 12..15)
  f32x4 acc30[8], acc31[8];
  #pragma unroll
  for (int s=0;s<8;++s)
    #pragma unroll
    for (int r=0;r<4;++r){
      const float b = sm.bc1[(s<<4)+(q<<2)+r];
      acc30[s][r] = b; acc31[s][r] = b;
    }
  #pragma unroll
  for (int t=0;t<4;++t){
    if (t < 3){ STAGE(13+t); WAITV2; } else { WAITV0; }
    BARF;
    #pragma unroll
    for (int s=0;s<8;++s){
      const s16x8 A = *(const s16x8*)(&sm.wbuf[t&1][(s<<10)+toff]);
      acc30[s] = MFMA(A, mb0[t], acc30[s]);
      acc31[s] = MFMA(A, mb1[t], acc31[s]);
    }
    EBAR;
  }

  // epilogue: coord scatter + m store
  float dot0 = 0.f, dot1 = 0.f;
  #pragma unroll
  for (int s=0;s<8;++s)
    #pragma unroll
    for (int r=0;r<4;++r){
      const int f = (s<<4)+(q<<2)+r;
      dot0 += silu_f(acc30[s][r]) * sm.wc2[f];
      dot1 += silu_f(acc31[s][r]) * sm.wc2[f];
    }
  dot0 += __shfl_xor(dot0, 16); dot0 += __shfl_xor(dot0, 32);
  dot1 += __shfl_xor(dot1, 16); dot1 += __shfl_xor(dot1, 32);
  const float cm0 = tanhf(dot0), cm1 = tanhf(dot1);
  if (q < 3){
    atomicAdd(&cu[(size_t)sm.col[el0]*3 + q], cm0 * sm.rdir[el0][q]);
    atomicAdd(&cu[(size_t)sm.col[el1]*3 + q], cm1 * sm.rdir[el1][q]);
  }
  if (CSR){
    unsigned short* mp0 = m_buf + (size_t)(ebase+el0)*HDIM + q8;
    unsigned short* mp1 = m_buf + (size_t)(ebase+el1)*HDIM + q8;
    #pragma unroll
    for (int t=0;t<4;++t){
      *(s16x8*)(mp0 + (t<<5)) = mb0[t];
      *(s16x8*)(mp1 + (t<<5)) = mb1[t];
    }
  } else {
    float* ap0 = agg + (size_t)sm.col[el0]*HDIM + (q<<2);
    float* ap1 = agg + (size_t)sm.col[el1]*HDIM + (q<<2);
    #pragma unroll
    for (int t=0;t<4;++t)
      #pragma unroll
      for (int j=0;j<8;++j){
        const int o = (((t<<1)+(j>>2))<<4) + (j&3);
        atomicAdd(ap0 + o, b2f((unsigned short)mb0[t][j]));
        atomicAdd(ap1 + o, b2f((unsigned short)mb1[t][j]));
      }
  }
}

// ---------------- per-layer node update ----------------
template<bool CSR>
__global__ __launch_bounds__(256) void k_node_mlp(
    float* __restrict__ hbuf, unsigned short* __restrict__ hb,
    float* __restrict__ xbuf,
    const unsigned short* __restrict__ m_buf, const float* __restrict__ agg,
    const int* __restrict__ off, const int* __restrict__ degi, const int* __restrict__ elist,
    const float* __restrict__ cu,
    const unsigned short* __restrict__ Wn1T, const float* __restrict__ bn1v,
    const unsigned short* __restrict__ Wn2T, const float* __restrict__ bn2v,
    const float* __restrict__ lng, const float* __restrict__ lnb)
{
  __shared__ float s_bn1[128], s_bn2[128], s_g[128], s_b[128];
  const int tid = threadIdx.x;
  const int nbase = blockIdx.x << 6;
  if (tid >= 128){
    const int f = tid - 128;
    s_bn1[f]=bn1v[f]; s_bn2[f]=bn2v[f]; s_g[f]=lng[f]; s_b[f]=lnb[f];
  } else if (tid < 64){
    const int n = nbase + tid;
    if (n < N_NODES){
      const float dd = (float)degi[n] + 1.0f;
      #pragma unroll
      for (int c=0;c<3;++c) xbuf[3*n+c] += cu[3*n+c] / dd;
    }
  }
  __syncthreads();

  const int lane = tid & 63, q = lane >> 4;
  const int q8 = q << 3;
  const int n = nbase + ((tid>>6)<<4) + (lane & 15);
  const bool valid = (n < N_NODES);
  const int nc = valid ? n : (N_NODES-1);
  const float* __restrict__ hp = hbuf + (size_t)nc*HDIM;
  const unsigned short* __restrict__ hbp = hb + (size_t)nc*HDIM;

  float aggv[4][8];
  #pragma unroll
  for (int kk=0;kk<4;++kk)
    #pragma unroll
    for (int j=0;j<8;++j) aggv[kk][j]=0.f;
  if (CSR){
    const int st = off[nc];
    const int cnt = degi[nc];
    for (int ii=0; ii<cnt; ++ii){
      const unsigned short* mrow = m_buf + (size_t)elist[st+ii]*HDIM;
      #pragma unroll
      for (int kk=0;kk<4;++kk){
        const s16x8 v = *(const s16x8*)(mrow + (kk<<5) + q8);
        #pragma unroll
        for (int j=0;j<8;++j) aggv[kk][j] += b2f((unsigned short)v[j]);
      }
    }
  } else {
    const float* ap = agg + (size_t)nc*HDIM;
    #pragma unroll
    for (int kk=0;kk<4;++kk){
      float4 a = *(const float4*)(ap + (kk<<5) + (q<<2));
      float4 b = *(const float4*)(ap + (kk<<5) + 16 + (q<<2));
      aggv[kk][0]=a.x; aggv[kk][1]=a.y; aggv[kk][2]=a.z; aggv[kk][3]=a.w;
      aggv[kk][4]=b.x; aggv[kk][5]=b.y; aggv[kk][6]=b.z; aggv[kk][7]=b.w;
    }
  }

  // GEMM1: [h | agg] (K=256) @ Wn1
  f32x4 acc[8];
  #pragma unroll
  for (int s=0;s<8;++s)
    #pragma unroll
    for (int r=0;r<4;++r) acc[s][r] = s_bn1[(s<<4)+(q<<2)+r];
  #pragma unroll
  for (int kk=0;kk<4;++kk){
    const s16x8 bf = *(const s16x8*)(hbp + (kk<<5) + q8);
    #pragma unroll
    for (int s=0;s<8;++s) acc[s] = MFMA(ldA(Wn1T, 256, s, kk, lane), bf, acc[s]);
  }
  #pragma unroll
  for (int kk=0;kk<4;++kk){
    s16x8 bf;
    #pragma unroll
    for (int j=0;j<8;++j) bf[j] = (short)f2b(aggv[kk][j]);
    #pragma unroll
    for (int s=0;s<8;++s) acc[s] = MFMA(ldA(Wn1T, 256, s, kk+4, lane), bf, acc[s]);
  }
  s16x8 sb[4];
  #pragma unroll
  for (int t=0;t<4;++t)
    #pragma unroll
    for (int j=0;j<8;++j)
      sb[t][j] = (short)f2b(silu_f(acc[(t<<1)+(j>>2)][j&3]));
  f32x4 acc2[8];
  #pragma unroll
  for (int s=0;s<8;++s)
    #pragma unroll
    for (int r=0;r<4;++r) acc2[s][r] = s_bn2[(s<<4)+(q<<2)+r];
  #pragma unroll
  for (int kk=0;kk<4;++kk){
    #pragma unroll
    for (int s=0;s<8;++s) acc2[s] = MFMA(ldA(Wn2T, 128, s, kk, lane), sb[kk], acc2[s]);
  }

  // residual + LayerNorm
  float v[8][4];
  float sum = 0.f;
  #pragma unroll
  for (int s=0;s<8;++s){
    float4 h4 = *(const float4*)(hp + (s<<4) + (q<<2));
    v[s][0] = h4.x + acc2[s][0]; v[s][1] = h4.y + acc2[s][1];
    v[s][2] = h4.z + acc2[s][2]; v[s][3] = h4.w + acc2[s][3];
    sum += v[s][0]+v[s][1]+v[s][2]+v[s][3];
  }
  sum += __shfl_xor(sum, 16);
  sum += __shfl_xor(sum, 32);
  const float mu = sum * (1.0f/128.0f);
  float vs = 0.f;
  #pragma unroll
  for (int s=0;s<8;++s)
    #pragma unroll
    for (int r=0;r<4;++r){ const float d = v[s][r]-mu; vs += d*d; }
  vs += __shfl_xor(vs, 16);
  vs += __shfl_xor(vs, 32);
  const float rs = rsqrtf(vs*(1.0f/128.0f) + 1e-5f);
  if (valid){
    float* op = hbuf + (size_t)n*HDIM;
    unsigned short* hbw = hb + (size_t)n*HDIM;
    #pragma unroll
    for (int s=0;s<8;++s){
      const int f0 = (s<<4)+(q<<2);
      float4 o;
      o.x = (v[s][0]-mu)*rs*s_g[f0+0] + s_b[f0+0];
      o.y = (v[s][1]-mu)*rs*s_g[f0+1] + s_b[f0+1];
      o.z = (v[s][2]-mu)*rs*s_g[f0+2] + s_b[f0+2];
      o.w = (v[s][3]-mu)*rs*s_g[f0+3] + s_b[f0+3];
      *(float4*)(op + f0) = o;
      ushort4 u; u.x=f2b(o.x); u.y=f2b(o.y); u.z=f2b(o.z); u.w=f2b(o.w);
      *(ushort4*)(hbw + ((s>>1)<<5) + q8 + ((s&1)<<2)) = u;
    }
  }
}

// ---------------- epsilon head: edge part (LDS-staged) ----------------
__global__ __launch_bounds__(256) void k_eps_edge(
    const unsigned short* __restrict__ hb, const float* __restrict__ xbuf,
    const int* __restrict__ rowi, const int* __restrict__ coli,
    const unsigned short* __restrict__ blob,
    const float* __restrict__ bem1v, const float* __restrict__ wem_rows,
    const float* __restrict__ bem2v, const float* __restrict__ bec1v,
    const float* __restrict__ Wec2, const float* __restrict__ bec2,
    float* __restrict__ epsb)
{
  __shared__ struct {
    alignas(16) unsigned char wbuf[2][8192];
    int row[128]; int col[128];
    float rel[128][3]; float dist[128];
    float b1[128], w4[4][128], b2[128], bc1[128], wc[3][128];
  } sm;
  const int tid = threadIdx.x;
  const int ebase = blockIdx.x << 7;
  const int lane = tid & 63, w = tid >> 6, q = lane >> 4;
  if (tid < 128){
    const int e = ebase + tid;
    const int r = rowi[e], c = coli[e];
    sm.row[tid]=r; sm.col[tid]=c;
    const float dx = xbuf[3*r+0]-xbuf[3*c+0];
    const float dy = xbuf[3*r+1]-xbuf[3*c+1];
    const float dz = xbuf[3*r+2]-xbuf[3*c+2];
    sm.rel[tid][0]=dx; sm.rel[tid][1]=dy; sm.rel[tid][2]=dz;
    sm.dist[tid] = sqrtf(dx*dx+dy*dy+dz*dz);
  } else {
    const int f = tid - 128;
    sm.b1[f]=bem1v[f];
    sm.w4[0][f]=wem_rows[f];     sm.w4[1][f]=wem_rows[128+f];
    sm.w4[2][f]=wem_rows[256+f]; sm.w4[3][f]=wem_rows[384+f];
    sm.b2[f]=bem2v[f]; sm.bc1[f]=bec1v[f];
    sm.wc[0][f]=Wec2[f*3+0]; sm.wc[1][f]=Wec2[f*3+1]; sm.wc[2][f]=Wec2[f*3+2];
  }
  STAGE(0);
  __syncthreads();

  const int toff = ((lane&15)<<6) + ((q ^ ((lane>>1)&3))<<4);
  const int q8 = q << 3;
  const int el0 = (w<<5) + (lane&15);
  const int el1 = el0 + 16;
  const unsigned short* __restrict__ hr0 = hb + (size_t)sm.row[el0]*HDIM;
  const unsigned short* __restrict__ hc0 = hb + (size_t)sm.col[el0]*HDIM;
  const unsigned short* __restrict__ hr1 = hb + (size_t)sm.row[el1]*HDIM;
  const unsigned short* __restrict__ hc1 = hb + (size_t)sm.col[el1]*HDIM;
  const float r00=sm.rel[el0][0], r01=sm.rel[el0][1], r02=sm.rel[el0][2], d0=sm.dist[el0];
  const float r10=sm.rel[el1][0], r11=sm.rel[el1][1], r12=sm.rel[el1][2], d1=sm.dist[el1];

  f32x4 acc0[8], acc1[8];
  #pragma unroll
  for (int s=0;s<8;++s)
    #pragma unroll
    for (int r=0;r<4;++r){
      const int f = (s<<4)+(q<<2)+r;
      acc0[s][r] = sm.b1[f] + r00*sm.w4[0][f] + r01*sm.w4[1][f] + r02*sm.w4[2][f] + d0*sm.w4[3][f];
      acc1[s][r] = sm.b1[f] + r10*sm.w4[0][f] + r11*sm.w4[1][f] + r12*sm.w4[2][f] + d1*sm.w4[3][f];
    }
  s16x8 B0 = *(const s16x8*)(hr0 + q8);
  s16x8 B1 = *(const s16x8*)(hr1 + q8);
  #pragma unroll
  for (int t=0;t<8;++t){
    STAGE(t+1);
    WAITV2; BARF;
    s16x8 nB0, nB1;
    if (t < 7){
      const int kk = t+1;
      const int ho = ((kk&3)<<5) + q8;
      nB0 = *(const s16x8*)(((kk<4)?hr0:hc0) + ho);
      nB1 = *(const s16x8*)(((kk<4)?hr1:hc1) + ho);
    }
    #pragma unroll
    for (int s=0;s<8;++s){
      const s16x8 A = *(const s16x8*)(&sm.wbuf[t&1][(s<<10)+toff]);
      acc0[s] = MFMA(A, B0, acc0[s]);
      acc1[s] = MFMA(A, B1, acc1[s]);
    }
    EBAR;
    if (t < 7){ B0 = nB0; B1 = nB1; }
  }

  s16x8 sb0[4], sb1[4];
  #pragma unroll
  for (int t=0;t<4;++t)
    #pragma unroll
    for (int j=0;j<8;++j){
      sb0[t][j] = (short)f2b(silu_f(acc0[(t<<1)+(j>>2)][j&3]));
      sb1[t][j] = (short)f2b(silu_f(acc1[(t<<1)+(j>>2)][j&3]));
    }
  f32x4 acc20[8], acc21[8];
  #pragma unroll
  for (int s=0;s<8;++s)
    #pragma unroll
    for (int r=0;r<4;++r){
      const float b = sm.b2[(s<<4)+(q<<2)+r];
      acc20[s][r] = b; acc21[s][r] = b;
    }
  #pragma unroll
  for (int t=0;t<4;++t){
    STAGE(9+t);
    WAITV2; BARF;
    #pragma unroll
    for (int s=0;s<8;++s){
      const s16x8 A = *(const s16x8*)(&sm.wbuf[t&1][(s<<10)+toff]);
      acc20[s] = MFMA(A, sb0[t], acc20[s]);
      acc21[s] = MFMA(A, sb1[t], acc21[s]);
    }
    EBAR;
  }
  s16x8 mb0[4], mb1[4];
  #pragma unroll
  for (int t=0;t<4;++t)
    #pragma unroll
    for (int j=0;j<8;++j){
      mb0[t][j] = (short)f2b(silu_f(acc20[(t<<1)+(j>>2)][j&3]));
      mb1[t][j] = (short)f2b(silu_f(acc21[(t<<1)+(j>>2)][j&3]));
    }
  f32x4 acc30[8], acc31[8];
  #pragma unroll
  for (int s=0;s<8;++s)
    #pragma unroll
    for (int r=0;r<4;++r){
      const float b = sm.bc1[(s<<4)+(q<<2)+r];
      acc30[s][r] = b; acc31[s][r] = b;
    }
  #pragma unroll
  for (int t=0;t<4;++t){
    if (t < 3){ STAGE(13+t); WAITV2; } else { WAITV0; }
    BARF;
    #pragma unroll
    for (int s=0;s<8;++s){
      const s16x8 A = *(const s16x8*)(&sm.wbuf[t&1][(s<<10)+toff]);
      acc30[s] = MFMA(A, mb0[t], acc30[s]);
      acc31[s] = MFMA(A, mb1[t], acc31[s]);
    }
    EBAR;
  }

  float e00=0.f,e01=0.f,e02=0.f, e10=0.f,e11=0.f,e12=0.f;
  #pragma unroll
  for (int s=0;s<8;++s)
    #pragma unroll
    for (int r=0;r<4;++r){
      const int f = (s<<4)+(q<<2)+r;
      const float ev0 = silu_f(acc30[s][r]);
      const float ev1 = silu_f(acc31[s][r]);
      e00 += ev0*sm.wc[0][f]; e01 += ev0*sm.wc[1][f]; e02 += ev0*sm.wc[2][f];
      e10 += ev1*sm.wc[0][f]; e11 += ev1*sm.wc[1][f]; e12 += ev1*sm.wc[2][f];
    }
  e00 += __shfl_xor(e00,16); e00 += __shfl_xor(e00,32);
  e01 += __shfl_xor(e01,16); e01 += __shfl_xor(e01,32);
  e02 += __shfl_xor(e02,16); e02 += __shfl_xor(e02,32);
  e10 += __shfl_xor(e10,16); e10 += __shfl_xor(e10,32);
  e11 += __shfl_xor(e11,16); e11 += __shfl_xor(e11,32);
  e12 += __shfl_xor(e12,16); e12 += __shfl_xor(e12,32);
  if (q < 3){
    const float v0 = (q==0)?e00:((q==1)?e01:e02);
    const float v1 = (q==0)?e10:((q==1)?e11:e12);
    const float bq = bec2[q];
    atomicAdd(&epsb[(size_t)sm.col[el0]*3 + q], v0 + bq);
    atomicAdd(&epsb[(size_t)sm.col[el1]*3 + q], v1 + bq);
  }
}

// ---------------- epsilon head: node part ----------------
__global__ __launch_bounds__(256) void k_eps_node(
    const float* __restrict__ hbuf, const float* __restrict__ xbuf,
    const unsigned short* __restrict__ Wh1T, const float* __restrict__ bh1v,
    const float* __restrict__ wh1_rows,
    const float* __restrict__ Wh2, const float* __restrict__ bh2,
    float* __restrict__ epsb)
{
  __shared__ float s_bh1[128], s_w3[3][128], s_wc[3][128];
  const int tid = threadIdx.x;
  if (tid >= 128){
    const int f = tid - 128;
    s_bh1[f]=bh1v[f];
    s_w3[0][f]=wh1_rows[f]; s_w3[1][f]=wh1_rows[128+f]; s_w3[2][f]=wh1_rows[256+f];
    s_wc[0][f]=Wh2[f*3+0]; s_wc[1][f]=Wh2[f*3+1]; s_wc[2][f]=Wh2[f*3+2];
  }
  __syncthreads();
  const int lane = tid & 63, q = lane >> 4;
  const int n = (blockIdx.x<<6) + ((tid>>6)<<4) + (lane & 15);
  const bool valid = n < N_NODES;
  const int nc = valid ? n : (N_NODES-1);
  const float* __restrict__ hp = hbuf + (size_t)nc*HDIM;
  const float x0 = xbuf[3*nc+0], x1 = xbuf[3*nc+1], x2 = xbuf[3*nc+2];
  f32x4 acc[8];
  #pragma unroll
  for (int s=0;s<8;++s)
    #pragma unroll
    for (int r=0;r<4;++r){
      const int f = (s<<4)+(q<<2)+r;
      acc[s][r] = s_bh1[f] + x0*s_w3[0][f] + x1*s_w3[1][f] + x2*s_w3[2][f];
    }
  #pragma unroll
  for (int kk=0;kk<4;++kk){
    const s16x8 bf = ldBf32(hp + (kk<<5), q);
    #pragma unroll
    for (int s=0;s<8;++s) acc[s] = MFMA(ldA(Wh1T, 128, s, kk, lane), bf, acc[s]);
  }
  float d0=0.f, d1=0.f, d2=0.f;
  #pragma unroll
  for (int s=0;s<8;++s)
    #pragma unroll
    for (int r=0;r<4;++r){
      const int f = (s<<4)+(q<<2)+r;
      const float ev = silu_f(acc[s][r]);
      d0 += ev*s_wc[0][f]; d1 += ev*s_wc[1][f]; d2 += ev*s_wc[2][f];
    }
  d0 += __shfl_xor(d0,16); d0 += __shfl_xor(d0,32);
  d1 += __shfl_xor(d1,16); d1 += __shfl_xor(d1,32);
  d2 += __shfl_xor(d2,16); d2 += __shfl_xor(d2,32);
  if (valid && q < 3){
    const float val = (q==0)?d0:((q==1)?d1:d2);
    epsb[(size_t)n*3 + q] += val + bh2[q];
  }
}

extern "C" void kernel_launch(void* const* d_in, const int* in_sizes, int n_in,
                              void* d_out, int out_size, void* d_ws, size_t ws_size,
                              hipStream_t stream)
{
  (void)in_sizes; (void)n_in; (void)out_size;
  const float* h_in  = (const float*)d_in[0];
  const float* x_in  = (const float*)d_in[1];
  const int*   eidx  = (const int*)d_in[2];
  const float* W_emb = (const float*)d_in[3];
  const float* b_emb = (const float*)d_in[4];
  const float* Wm1 = (const float*)d_in[5];
  const float* bm1 = (const float*)d_in[6];
  const float* Wm2 = (const float*)d_in[7];
  const float* bm2 = (const float*)d_in[8];
  const float* Wc1 = (const float*)d_in[9];
  const float* bc1 = (const float*)d_in[10];
  const float* Wc2 = (const float*)d_in[11];
  const float* Wn1 = (const float*)d_in[12];
  const float* bn1 = (const float*)d_in[13];
  const float* Wn2 = (const float*)d_in[14];
  const float* bn2 = (const float*)d_in[15];
  const float* lng = (const float*)d_in[16];
  const float* lnb = (const float*)d_in[17];
  const float* Wem1 = (const float*)d_in[18];
  const float* bem1 = (const float*)d_in[19];
  const float* Wem2 = (const float*)d_in[20];
  const float* bem2 = (const float*)d_in[21];
  const float* Wec1 = (const float*)d_in[22];
  const float* bec1 = (const float*)d_in[23];
  const float* Wec2 = (const float*)d_in[24];
  const float* bec2 = (const float*)d_in[25];
  const float* Wh1 = (const float*)d_in[26];
  const float* bh1 = (const float*)d_in[27];
  const float* Wh2 = (const float*)d_in[28];
  const float* bh2 = (const float*)d_in[29];

  const int* rowi = eidx;
  const int* coli = eidx + N_EDGES;

  float* hbuf = (float*)d_out;
  float* xbuf = hbuf + (size_t)N_NODES*HDIM;
  float* epsb = xbuf + (size_t)N_NODES*3;

  char* wp = (char*)d_ws;
  auto alloc = [&](size_t bytes)->char*{
    char* p = wp; wp += (bytes + 255) & ~(size_t)255; return p;
  };
  unsigned short* WembT = (unsigned short*)alloc((size_t)128*64*2);
  unsigned short *Wn1T[NLAYERS], *Wn2T[NLAYERS];
  for (int i=0;i<NLAYERS;++i){
    Wn1T[i] = (unsigned short*)alloc((size_t)128*256*2);
    Wn2T[i] = (unsigned short*)alloc((size_t)128*128*2);
  }
  unsigned short* Wh1T  = (unsigned short*)alloc((size_t)128*128*2);
  unsigned short* blobL = (unsigned short*)alloc((size_t)NLAYERS*65536*2);
  unsigned short* blobE = (unsigned short*)alloc((size_t)65536*2);
  unsigned short* hb    = (unsigned short*)alloc((size_t)N_NODES*HDIM*2);
  int* degi   = (int*)alloc((size_t)N_NODES*4);
  int* offv   = (int*)alloc((size_t)N_NODES*4);
  int* cursor = (int*)alloc((size_t)N_NODES*4);
  int* bsum   = (int*)alloc(4096);
  float* cu   = (float*)alloc((size_t)N_NODES*3*4);
  int* elist  = (int*)alloc((size_t)N_EDGES*4);
  char* big   = alloc((size_t)N_EDGES*HDIM*2);       // m_buf (CSR) or agg (atomic)
  const bool use_csr = ((size_t)(wp - (char*)d_ws) <= ws_size);
  unsigned short* m_buf = (unsigned short*)big;
  float* agg = (float*)big;

  auto conv = [&](const float* W, unsigned short* WT, int kshift){
    const int tot = 128 << kshift;
    k_conv<<<dim3((tot+255)/256), dim3(256), 0, stream>>>(W, WT, kshift);
  };
  conv(W_emb, WembT, 6);
  for (int i=0;i<NLAYERS;++i){
    conv(Wn1 + (size_t)i*256*128, Wn1T[i], 8);
    conv(Wn2 + (size_t)i*128*128, Wn2T[i], 7);
  }
  conv(Wh1,  Wh1T,  7);
  for (int i=0;i<NLAYERS;++i)
    k_conv_blob<<<dim3(256), dim3(256), 0, stream>>>(
        Wm1 + (size_t)i*257*128, Wm2 + (size_t)i*128*128, Wc1 + (size_t)i*128*128,
        blobL + (size_t)i*65536);
  k_conv_blob<<<dim3(256), dim3(256), 0, stream>>>(Wem1, Wem2, Wec1, blobE);

  hipMemsetAsync(degi, 0, (size_t)N_NODES*4, stream);
  k_degree<<<dim3((N_EDGES+255)/256), dim3(256), 0, stream>>>(coli, degi);
  const int nb = (N_NODES + 255)/256;
  if (use_csr){
    k_scanA<<<dim3(nb), dim3(256), 0, stream>>>(degi, offv, bsum);
    k_scanB<<<dim3(1), dim3(256), 0, stream>>>(bsum, nb);
    k_scanC<<<dim3(nb), dim3(256), 0, stream>>>(offv, bsum, cursor);
    k_fill<<<dim3((N_EDGES+255)/256), dim3(256), 0, stream>>>(coli, cursor, elist);
  }
  k_xcopy<<<dim3((N_NODES*3+255)/256), dim3(256), 0, stream>>>(x_in, xbuf);
  k_embed<<<dim3((N_NODES+63)/64), dim3(256), 0, stream>>>(h_in, WembT, b_emb, hbuf, hb);

  for (int i=0;i<NLAYERS;++i){
    hipMemsetAsync(cu, 0, (size_t)N_NODES*3*4, stream);
    if (!use_csr) hipMemsetAsync(agg, 0, (size_t)N_NODES*HDIM*4, stream);
    const float* wm1r256 = Wm1 + (size_t)i*257*128 + (size_t)256*128;
    if (use_csr){
      k_edge_mlp<true><<<dim3(N_EDGES/128), dim3(256), 0, stream>>>(
        hb, xbuf, rowi, coli, blobL + (size_t)i*65536,
        bm1 + i*128, wm1r256, bm2 + i*128, bc1 + i*128, Wc2 + i*128,
        m_buf, agg, cu);
      k_node_mlp<true><<<dim3((N_NODES+63)/64), dim3(256), 0, stream>>>(
        hbuf, hb, xbuf, m_buf, agg, offv, degi, elist, cu,
        Wn1T[i], bn1 + i*128, Wn2T[i], bn2 + i*128, lng + i*128, lnb + i*128);
    } else {
      k_edge_mlp<false><<<dim3(N_EDGES/128), dim3(256), 0, stream>>>(
        hb, xbuf, rowi, coli, blobL + (size_t)i*65536,
        bm1 + i*128, wm1r256, bm2 + i*128, bc1 + i*128, Wc2 + i*128,
        m_buf, agg, cu);
      k_node_mlp<false><<<dim3((N_NODES+63)/64), dim3(256), 0, stream>>>(
        hbuf, hb, xbuf, m_buf, agg, offv, degi, elist, cu,
        Wn1T[i], bn1 + i*128, Wn2T[i], bn2 + i*128, lng + i*128, lnb + i*128);
    }
  }
  hipMemsetAsync(epsb, 0, (size_t)N_NODES*3*4, stream);
  k_eps_edge<<<dim3(N_EDGES/128), dim3(256), 0, stream>>>(
    hb, xbuf, rowi, coli, blobE,
    bem1, Wem1 + (size_t)256*128, bem2, bec1, Wec2, bec2, epsb);
  k_eps_node<<<dim3((N_NODES+63)/64), dim3(256), 0, stream>>>(
    hbuf, xbuf, Wh1T, bh1, Wh1 + (size_t)128*128, Wh2, bh2, epsb);
}

// Round 3
// 1263.533 us; speedup vs baseline: 4.3070x; 1.0940x over previous
//
#include <hip/hip_runtime.h>

#define N_NODES 50000
#define N_EDGES 640000
#define HDIM    128
#define NLAYERS 3

typedef __attribute__((ext_vector_type(4))) float f32x4;
typedef short s16x8 __attribute__((ext_vector_type(8)));
typedef __bf16 bf16v8 __attribute__((ext_vector_type(8)));

static __device__ __forceinline__ unsigned short f2b(float f){
  unsigned int u = __float_as_uint(f);
  unsigned int r = u + 0x7FFFu + ((u >> 16) & 1u);
  return (unsigned short)(r >> 16);
}
static __device__ __forceinline__ float b2f(unsigned short h){
  return __uint_as_float(((unsigned int)h) << 16);
}
static __device__ __forceinline__ float silu_f(float x){
  return x / (1.0f + __expf(-x));
}
static __device__ __forceinline__ unsigned int cvt2(float a, float b){
  unsigned int r;
  asm("v_cvt_pk_bf16_f32 %0, %1, %2" : "=v"(r) : "v"(a), "v"(b));
  return r;
}
static __device__ __forceinline__ s16x8 siluPack(const f32x4 a, const f32x4 b){
  union { unsigned int u[4]; s16x8 v; } r;
  r.u[0] = cvt2(silu_f(a[0]), silu_f(a[1]));
  r.u[1] = cvt2(silu_f(a[2]), silu_f(a[3]));
  r.u[2] = cvt2(silu_f(b[0]), silu_f(b[1]));
  r.u[3] = cvt2(silu_f(b[2]), silu_f(b[3]));
  return r.v;
}
static __device__ __forceinline__ f32x4 MFMA(s16x8 a, s16x8 b, f32x4 c){
  return __builtin_amdgcn_mfma_f32_16x16x32_bf16(
      __builtin_bit_cast(bf16v8, a), __builtin_bit_cast(bf16v8, b), c, 0, 0, 0);
}

// A-fragment from global (node/embed kernels): WT[out][K] row-major
static __device__ __forceinline__ s16x8 ldA(const unsigned short* __restrict__ WT,
                                            int K, int s, int kk, int lane){
  const unsigned short* p = WT + (size_t)((s<<4) + (lane&15))*K + (kk<<5) + ((lane>>4)<<2);
  ushort4 a = *(const ushort4*)p;
  ushort4 b = *(const ushort4*)(p + 16);
  s16x8 r;
  r[0]=(short)a.x; r[1]=(short)a.y; r[2]=(short)a.z; r[3]=(short)a.w;
  r[4]=(short)b.x; r[5]=(short)b.y; r[6]=(short)b.z; r[7]=(short)b.w;
  return r;
}
static __device__ __forceinline__ s16x8 ldBf32(const float* __restrict__ p, int q){
  float4 a = *(const float4*)(p + (q<<2));
  float4 b = *(const float4*)(p + 16 + (q<<2));
  s16x8 r;
  r[0]=(short)f2b(a.x); r[1]=(short)f2b(a.y); r[2]=(short)f2b(a.z); r[3]=(short)f2b(a.w);
  r[4]=(short)f2b(b.x); r[5]=(short)f2b(b.y); r[6]=(short)f2b(b.z); r[7]=(short)f2b(b.w);
  return r;
}

#define GLL(SRC, DST) __builtin_amdgcn_global_load_lds( \
    (const __attribute__((address_space(1))) void*)(SRC), \
    (__attribute__((address_space(3))) void*)(DST), 16, 0, 0)
// stage 2 tiles (8192 elems) into wbuf[BUF]; per wave 2048 elems = 4x 1KB chunks
#define STG2(T0,BUF) do{ \
    const unsigned short* _s = blob + (((size_t)(T0))<<12) + (w<<11) + (lane<<3); \
    unsigned char* _d = &sm.wbuf[BUF][(w<<12) + (lane<<4)]; \
    GLL(_s, _d); GLL(_s+512, _d+1024); GLL(_s+1024, _d+2048); GLL(_s+1536, _d+3072); \
  }while(0)
// stage 1 tile (4096 elems); per wave 1024 elems = 2 chunks
#define STG1(T0,BUF) do{ \
    const unsigned short* _s = blob + (((size_t)(T0))<<12) + (w<<10) + (lane<<3); \
    unsigned char* _d = &sm.wbuf[BUF][(w<<11) + (lane<<4)]; \
    GLL(_s, _d); GLL(_s+512, _d+1024); \
  }while(0)
#define WAITV(N) asm volatile("s_waitcnt vmcnt(" #N ")" ::: "memory")
#define BARF do{ __builtin_amdgcn_s_barrier(); asm volatile("" ::: "memory"); }while(0)
#define EBAR do{ asm volatile("" ::: "memory"); __builtin_amdgcn_s_barrier(); }while(0)

#define PH2(BUF, BEXPR, ACC) do{ \
  _Pragma("unroll") for (int ti=0; ti<2; ++ti){ \
    _Pragma("unroll") for (int s=0;s<8;++s){ \
      const s16x8 _A = *(const s16x8*)&sm.wbuf[BUF][(ti<<13)+(s<<10)+toff]; \
      _Pragma("unroll") for (int e=0;e<4;++e) ACC[e][s] = MFMA(_A, (BEXPR), ACC[e][s]); \
    } } }while(0)
#define PH1(BUF, BEXPR, ACC) do{ \
  _Pragma("unroll") for (int s=0;s<8;++s){ \
    const s16x8 _A = *(const s16x8*)&sm.wbuf[BUF][(s<<10)+toff]; \
    _Pragma("unroll") for (int e=0;e<4;++e) ACC[e][s] = MFMA(_A, (BEXPR), ACC[e][s]); \
  } }while(0)

// ---------------- weight convert+transpose (f32 [K][128] -> bf16 [128][K]) ----
__global__ void k_conv(const float* __restrict__ W, unsigned short* __restrict__ WT, int kshift){
  const int K = 1 << kshift;
  const int idx = (blockIdx.x<<8) + threadIdx.x;
  if (idx < (K<<7)){
    const int n = idx >> kshift;
    const int k = idx & (K-1);
    WT[idx] = f2b(W[(size_t)k*HDIM + n]);
  }
}

// blob: 17 tiles of 4096 bf16.  t=0: aux tile (k-slots 0..naux-1 = aux rows,
// k-slot 16 = bias row); t=1..8: W1 chunk t-1; t=9..12: W2; t=13..16: W3.
// elem i: n=(i>>5)&127, slot=(i>>3)&3, j=i&7; q=slot^((n>>1)&3);
// kl=((j>>2)<<4)+(q<<2)+(j&3)
__global__ void k_conv_blob(const float* __restrict__ W1, const float* __restrict__ W2,
                            const float* __restrict__ W3, const float* __restrict__ aux,
                            const float* __restrict__ bias, int naux,
                            unsigned short* __restrict__ blob){
  const int i = (blockIdx.x<<8) + threadIdx.x;
  if (i >= 17*4096) return;
  const int t = i >> 12;
  const int n = (i >> 5) & 127;
  const int slot = (i >> 3) & 3;
  const int j = i & 7;
  const int q = slot ^ ((n >> 1) & 3);
  const int kl = ((j >> 2) << 4) + (q << 2) + (j & 3);
  float v;
  if (t == 0)      v = (kl < naux) ? aux[(size_t)kl*HDIM + n] : (kl == 16 ? bias[n] : 0.f);
  else if (t < 9)  v = W1[(size_t)(((t-1)<<5)+kl)*HDIM + n];
  else if (t < 13) v = W2[(size_t)(((t-9)<<5)+kl)*HDIM + n];
  else             v = W3[(size_t)(((t-13)<<5)+kl)*HDIM + n];
  blob[i] = f2b(v);
}

// ---------------- CSR build ----------------
__global__ void k_degree(const int* __restrict__ coli, int* __restrict__ degi){
  const int e = (blockIdx.x<<8) + threadIdx.x;
  if (e < N_EDGES) atomicAdd(&degi[coli[e]], 1);
}
__global__ void k_scanA(const int* __restrict__ degi, int* __restrict__ off, int* __restrict__ bsum){
  const int t = threadIdx.x, b = blockIdx.x;
  const int i = (b<<8) + t;
  const int v = (i < N_NODES) ? degi[i] : 0;
  int x = v;
  const int lane = t & 63;
  #pragma unroll
  for (int d=1; d<64; d<<=1){ int y = __shfl_up(x, d); if (lane >= d) x += y; }
  __shared__ int wsum[4];
  if (lane == 63) wsum[t>>6] = x;
  __syncthreads();
  int wo = 0;
  #pragma unroll
  for (int w=0; w<4; ++w) if (w < (t>>6)) wo += wsum[w];
  const int incl = x + wo;
  if (i < N_NODES) off[i] = incl - v;
  if (t == 255) bsum[b] = incl;
}
__global__ void k_scanB(int* __restrict__ bsum, int nb){
  const int t = threadIdx.x;
  const int v = (t < nb) ? bsum[t] : 0;
  int x = v;
  const int lane = t & 63;
  #pragma unroll
  for (int d=1; d<64; d<<=1){ int y = __shfl_up(x, d); if (lane >= d) x += y; }
  __shared__ int wsum[4];
  if (lane == 63) wsum[t>>6] = x;
  __syncthreads();
  int wo = 0;
  #pragma unroll
  for (int w=0; w<4; ++w) if (w < (t>>6)) wo += wsum[w];
  const int incl = x + wo;
  if (t < nb) bsum[t] = incl - v;
}
__global__ void k_scanC(int* __restrict__ off, const int* __restrict__ bsum, int* __restrict__ cursor){
  const int i = (blockIdx.x<<8) + threadIdx.x;
  if (i < N_NODES){
    const int o = off[i] + bsum[i>>8];
    off[i] = o;
    cursor[i] = o;
  }
}
__global__ void k_fill(const int* __restrict__ coli, int* __restrict__ cursor, int* __restrict__ perm){
  const int e = (blockIdx.x<<8) + threadIdx.x;
  if (e < N_EDGES){
    const int p = atomicAdd(&cursor[coli[e]], 1);
    perm[e] = p;
  }
}
__global__ void k_xcopy(const float* __restrict__ xin, float* __restrict__ xbuf){
  const int i = (blockIdx.x<<8) + threadIdx.x;
  if (i < N_NODES*3) xbuf[i] = xin[i];
}

// ---------------- embedding: h = h_in @ W_emb + b_emb (+ bf16 mirror) --------
__global__ __launch_bounds__(256) void k_embed(
    const float* __restrict__ hin, const unsigned short* __restrict__ WembT,
    const float* __restrict__ bemb, float* __restrict__ hbuf,
    unsigned short* __restrict__ hb)
{
  __shared__ float s_b[128];
  const int tid = threadIdx.x;
  if (tid < 128) s_b[tid] = bemb[tid];
  __syncthreads();
  const int lane = tid & 63, q = lane>>4;
  const int n = (blockIdx.x<<6) + ((tid>>6)<<4) + (lane&15);
  const bool valid = n < N_NODES;
  const int nc = valid ? n : (N_NODES-1);
  const float* __restrict__ hp = hin + (size_t)nc*64;
  f32x4 acc[8];
  #pragma unroll
  for (int s=0;s<8;++s)
    #pragma unroll
    for (int r=0;r<4;++r) acc[s][r] = s_b[(s<<4)+(q<<2)+r];
  #pragma unroll
  for (int kk=0;kk<2;++kk){
    const s16x8 bf = ldBf32(hp + (kk<<5), q);
    #pragma unroll
    for (int s=0;s<8;++s) acc[s] = MFMA(ldA(WembT, 64, s, kk, lane), bf, acc[s]);
  }
  if (valid){
    float* op = hbuf + (size_t)n*HDIM;
    unsigned short* hbw = hb + (size_t)n*HDIM;
    #pragma unroll
    for (int s=0;s<8;++s){
      float4 o; o.x=acc[s][0]; o.y=acc[s][1]; o.z=acc[s][2]; o.w=acc[s][3];
      *(float4*)(op + (s<<4) + (q<<2)) = o;
      ushort4 u; u.x=f2b(o.x); u.y=f2b(o.y); u.z=f2b(o.z); u.w=f2b(o.w);
      *(ushort4*)(hbw + ((s>>1)<<5) + (q<<3) + ((s&1)<<2)) = u;
    }
  }
}

// ---------------- per-layer edge MLP (256 edges/block, 4 edges/thread) -------
template<bool CSR>
__global__ __launch_bounds__(256,2) void k_edge_mlp(
    const unsigned short* __restrict__ hb, const float* __restrict__ xbuf,
    const int* __restrict__ rowi, const int* __restrict__ coli,
    const int* __restrict__ perm, const unsigned short* __restrict__ blob,
    const float* __restrict__ bm2v, const float* __restrict__ bc1v,
    const float* __restrict__ wc2v,
    unsigned short* __restrict__ m_buf, float* __restrict__ agg,
    float* __restrict__ cu)
{
  __shared__ struct {
    alignas(16) unsigned char wbuf[2][16384];
    int row[256], col[256], prm[256];
    float dist[256]; float rdir[256][3];
    float b2[128], bc1[128], wc2[128];
  } sm;
  const int tid = threadIdx.x, lane = tid & 63, w = tid >> 6, q = lane >> 4;
  const int q8 = q << 3;
  const int ebase = blockIdx.x << 8;
  {
    const int e = ebase + tid;
    const int r = rowi[e], c = coli[e];
    sm.row[tid] = r; sm.col[tid] = c;
    if (CSR) sm.prm[tid] = perm[e];
    const float dx = xbuf[3*r+0] - xbuf[3*c+0];
    const float dy = xbuf[3*r+1] - xbuf[3*c+1];
    const float dz = xbuf[3*r+2] - xbuf[3*c+2];
    const float d = sqrtf(dx*dx + dy*dy + dz*dz);
    sm.dist[tid] = d;
    const float inv = 1.0f / (d + 1e-8f);
    sm.rdir[tid][0] = dx*inv; sm.rdir[tid][1] = dy*inv; sm.rdir[tid][2] = dz*inv;
  }
  if (tid < 128){ sm.b2[tid]=bm2v[tid]; sm.bc1[tid]=bc1v[tid]; sm.wc2[tid]=wc2v[tid]; }
  STG2(0,0); STG2(2,1);
  __syncthreads();

  const int toff = ((lane&15)<<6) + ((q ^ ((lane>>1)&3))<<4);
  int rn[4], cn[4];
  #pragma unroll
  for (int e=0;e<4;++e){
    const int el = (w<<6) + (e<<4) + (lane&15);
    rn[e] = sm.row[el]; cn[e] = sm.col[el];
  }
  s16x8 BA[4][2], BB[4][2];
  #pragma unroll
  for (int e=0;e<4;++e){
    const int el = (w<<6) + (e<<4) + (lane&15);
    s16x8 bx = {0,0,0,0,0,0,0,0};
    if (q == 0){ bx[0] = (short)f2b(sm.dist[el]); bx[4] = (short)0x3F80; }
    BA[e][0] = bx;
    BA[e][1] = *(const s16x8*)(hb + ((size_t)rn[e]<<7) + q8);            // kk0
  }
  f32x4 acc[4][8] = {};

  // P0 tiles{0,1} buf0
  BARF;
  #pragma unroll
  for (int e=0;e<4;++e){
    BB[e][0] = *(const s16x8*)(hb + ((size_t)rn[e]<<7) + 32 + q8);       // kk1
    BB[e][1] = *(const s16x8*)(hb + ((size_t)rn[e]<<7) + 64 + q8);       // kk2
  }
  PH2(0, BA[e][ti], acc);
  EBAR; STG2(4,0);
  // P1 tiles{2,3} buf1
  BARF;
  #pragma unroll
  for (int e=0;e<4;++e){
    BA[e][0] = *(const s16x8*)(hb + ((size_t)rn[e]<<7) + 96 + q8);       // kk3
    BA[e][1] = *(const s16x8*)(hb + ((size_t)cn[e]<<7) + q8);            // kk4
  }
  PH2(1, BB[e][ti], acc);
  EBAR; STG2(6,1);
  // P2 tiles{4,5} buf0
  WAITV(12); BARF;
  #pragma unroll
  for (int e=0;e<4;++e){
    BB[e][0] = *(const s16x8*)(hb + ((size_t)cn[e]<<7) + 32 + q8);       // kk5
    BB[e][1] = *(const s16x8*)(hb + ((size_t)cn[e]<<7) + 64 + q8);       // kk6
  }
  PH2(0, BA[e][ti], acc);
  EBAR; STG1(8,0);
  // P3 tiles{6,7} buf1
  WAITV(10); BARF;
  #pragma unroll
  for (int e=0;e<4;++e)
    BA[e][0] = *(const s16x8*)(hb + ((size_t)cn[e]<<7) + 96 + q8);       // kk7
  PH2(1, BB[e][ti], acc);
  EBAR; STG2(9,1);
  // P4 tile{8} buf0
  WAITV(8); BARF;
  PH1(0, BA[e][0], acc);
  EBAR; STG2(11,0);

  // convert -> sb
  s16x8 sb[4][4];
  #pragma unroll
  for (int e=0;e<4;++e)
    #pragma unroll
    for (int c=0;c<4;++c) sb[e][c] = siluPack(acc[e][2*c], acc[e][2*c+1]);
  f32x4 acc2[4][8];
  #pragma unroll
  for (int s=0;s<8;++s){
    const f32x4 b = *(const f32x4*)&sm.b2[(s<<4)+(q<<2)];
    #pragma unroll
    for (int e=0;e<4;++e) acc2[e][s] = b;
  }
  // P5 tiles{9,10} buf1
  WAITV(4); BARF;
  PH2(1, sb[e][ti], acc2);
  EBAR; STG2(13,1);
  // P6 tiles{11,12} buf0
  WAITV(4); BARF;
  PH2(0, sb[e][2+ti], acc2);
  EBAR; STG2(15,0);

  s16x8 mb[4][4];
  #pragma unroll
  for (int e=0;e<4;++e)
    #pragma unroll
    for (int c=0;c<4;++c) mb[e][c] = siluPack(acc2[e][2*c], acc2[e][2*c+1]);
  f32x4 acc3[4][8];
  #pragma unroll
  for (int s=0;s<8;++s){
    const f32x4 b = *(const f32x4*)&sm.bc1[(s<<4)+(q<<2)];
    #pragma unroll
    for (int e=0;e<4;++e) acc3[e][s] = b;
  }
  // P7 tiles{13,14} buf1
  WAITV(4); BARF;
  PH2(1, mb[e][ti], acc3);
  EBAR;
  // P8 tiles{15,16} buf0
  WAITV(0); BARF;
  PH2(0, mb[e][2+ti], acc3);

  // epilogue
  float dot[4] = {0.f,0.f,0.f,0.f};
  #pragma unroll
  for (int s=0;s<8;++s){
    const f32x4 wv = *(const f32x4*)&sm.wc2[(s<<4)+(q<<2)];
    #pragma unroll
    for (int e=0;e<4;++e)
      #pragma unroll
      for (int r=0;r<4;++r) dot[e] += silu_f(acc3[e][s][r]) * wv[r];
  }
  #pragma unroll
  for (int e=0;e<4;++e){
    dot[e] += __shfl_xor(dot[e], 16);
    dot[e] += __shfl_xor(dot[e], 32);
    const float cm = tanhf(dot[e]);
    const int el = (w<<6) + (e<<4) + (lane&15);
    if (q < 3) atomicAdd(&cu[(size_t)cn[e]*3 + q], cm * sm.rdir[el][q]);
  }
  if (CSR){
    #pragma unroll
    for (int e=0;e<4;++e){
      const int el = (w<<6) + (e<<4) + (lane&15);
      unsigned short* mp = m_buf + ((size_t)sm.prm[el]<<7) + q8;
      #pragma unroll
      for (int c=0;c<4;++c) *(s16x8*)(mp + (c<<5)) = mb[e][c];
    }
  } else {
    #pragma unroll
    for (int e=0;e<4;++e){
      float* ap = agg + (size_t)cn[e]*HDIM + (q<<2);
      #pragma unroll
      for (int c=0;c<4;++c)
        #pragma unroll
        for (int j=0;j<8;++j){
          const int o = (((c<<1)+(j>>2))<<4) + (j&3);
          atomicAdd(ap + o, b2f((unsigned short)mb[e][c][j]));
        }
    }
  }
}

// ---------------- per-layer node update (sequential m_buf via perm) ----------
template<bool CSR>
__global__ __launch_bounds__(256) void k_node_mlp(
    float* __restrict__ hbuf, unsigned short* __restrict__ hb,
    float* __restrict__ xbuf,
    const unsigned short* __restrict__ m_buf, const float* __restrict__ agg,
    const int* __restrict__ off, const int* __restrict__ degi,
    const float* __restrict__ cu,
    const unsigned short* __restrict__ Wn1T, const float* __restrict__ bn1v,
    const unsigned short* __restrict__ Wn2T, const float* __restrict__ bn2v,
    const float* __restrict__ lng, const float* __restrict__ lnb)
{
  __shared__ float s_bn1[128], s_bn2[128], s_g[128], s_b[128];
  const int tid = threadIdx.x;
  const int nbase = blockIdx.x << 6;
  if (tid >= 128){
    const int f = tid - 128;
    s_bn1[f]=bn1v[f]; s_bn2[f]=bn2v[f]; s_g[f]=lng[f]; s_b[f]=lnb[f];
  } else if (tid < 64){
    const int n = nbase + tid;
    if (n < N_NODES){
      const float dd = (float)degi[n] + 1.0f;
      #pragma unroll
      for (int c=0;c<3;++c) xbuf[3*n+c] += cu[3*n+c] / dd;
    }
  }
  __syncthreads();

  const int lane = tid & 63, q = lane >> 4;
  const int q8 = q << 3;
  const int n = nbase + ((tid>>6)<<4) + (lane & 15);
  const bool valid = (n < N_NODES);
  const int nc = valid ? n : (N_NODES-1);
  const float* __restrict__ hp = hbuf + (size_t)nc*HDIM;
  const unsigned short* __restrict__ hbp = hb + (size_t)nc*HDIM;

  float aggv[4][8];
  #pragma unroll
  for (int kk=0;kk<4;++kk)
    #pragma unroll
    for (int j=0;j<8;++j) aggv[kk][j]=0.f;
  if (CSR){
    const int st = off[nc];
    const int cnt = degi[nc];
    for (int ii=0; ii<cnt; ++ii){
      const unsigned short* mrow = m_buf + ((size_t)(st+ii)<<7);
      #pragma unroll
      for (int kk=0;kk<4;++kk){
        const s16x8 v = *(const s16x8*)(mrow + (kk<<5) + q8);
        #pragma unroll
        for (int j=0;j<8;++j) aggv[kk][j] += b2f((unsigned short)v[j]);
      }
    }
  } else {
    const float* ap = agg + (size_t)nc*HDIM;
    #pragma unroll
    for (int kk=0;kk<4;++kk){
      float4 a = *(const float4*)(ap + (kk<<5) + (q<<2));
      float4 b = *(const float4*)(ap + (kk<<5) + 16 + (q<<2));
      aggv[kk][0]=a.x; aggv[kk][1]=a.y; aggv[kk][2]=a.z; aggv[kk][3]=a.w;
      aggv[kk][4]=b.x; aggv[kk][5]=b.y; aggv[kk][6]=b.z; aggv[kk][7]=b.w;
    }
  }

  f32x4 acc[8];
  #pragma unroll
  for (int s=0;s<8;++s)
    #pragma unroll
    for (int r=0;r<4;++r) acc[s][r] = s_bn1[(s<<4)+(q<<2)+r];
  #pragma unroll
  for (int kk=0;kk<4;++kk){
    const s16x8 bf = *(const s16x8*)(hbp + (kk<<5) + q8);
    #pragma unroll
    for (int s=0;s<8;++s) acc[s] = MFMA(ldA(Wn1T, 256, s, kk, lane), bf, acc[s]);
  }
  #pragma unroll
  for (int kk=0;kk<4;++kk){
    s16x8 bf;
    #pragma unroll
    for (int j=0;j<8;++j) bf[j] = (short)f2b(aggv[kk][j]);
    #pragma unroll
    for (int s=0;s<8;++s) acc[s] = MFMA(ldA(Wn1T, 256, s, kk+4, lane), bf, acc[s]);
  }
  s16x8 sb[4];
  #pragma unroll
  for (int t=0;t<4;++t)
    #pragma unroll
    for (int j=0;j<8;++j)
      sb[t][j] = (short)f2b(silu_f(acc[(t<<1)+(j>>2)][j&3]));
  f32x4 acc2[8];
  #pragma unroll
  for (int s=0;s<8;++s)
    #pragma unroll
    for (int r=0;r<4;++r) acc2[s][r] = s_bn2[(s<<4)+(q<<2)+r];
  #pragma unroll
  for (int kk=0;kk<4;++kk){
    #pragma unroll
    for (int s=0;s<8;++s) acc2[s] = MFMA(ldA(Wn2T, 128, s, kk, lane), sb[kk], acc2[s]);
  }

  float v[8][4];
  float sum = 0.f;
  #pragma unroll
  for (int s=0;s<8;++s){
    float4 h4 = *(const float4*)(hp + (s<<4) + (q<<2));
    v[s][0] = h4.x + acc2[s][0]; v[s][1] = h4.y + acc2[s][1];
    v[s][2] = h4.z + acc2[s][2]; v[s][3] = h4.w + acc2[s][3];
    sum += v[s][0]+v[s][1]+v[s][2]+v[s][3];
  }
  sum += __shfl_xor(sum, 16);
  sum += __shfl_xor(sum, 32);
  const float mu = sum * (1.0f/128.0f);
  float vs = 0.f;
  #pragma unroll
  for (int s=0;s<8;++s)
    #pragma unroll
    for (int r=0;r<4;++r){ const float d = v[s][r]-mu; vs += d*d; }
  vs += __shfl_xor(vs, 16);
  vs += __shfl_xor(vs, 32);
  const float rs = rsqrtf(vs*(1.0f/128.0f) + 1e-5f);
  if (valid){
    float* op = hbuf + (size_t)n*HDIM;
    unsigned short* hbw = hb + (size_t)n*HDIM;
    #pragma unroll
    for (int s=0;s<8;++s){
      const int f0 = (s<<4)+(q<<2);
      float4 o;
      o.x = (v[s][0]-mu)*rs*s_g[f0+0] + s_b[f0+0];
      o.y = (v[s][1]-mu)*rs*s_g[f0+1] + s_b[f0+1];
      o.z = (v[s][2]-mu)*rs*s_g[f0+2] + s_b[f0+2];
      o.w = (v[s][3]-mu)*rs*s_g[f0+3] + s_b[f0+3];
      *(float4*)(op + f0) = o;
      ushort4 u; u.x=f2b(o.x); u.y=f2b(o.y); u.z=f2b(o.z); u.w=f2b(o.w);
      *(ushort4*)(hbw + ((s>>1)<<5) + q8 + ((s&1)<<2)) = u;
    }
  }
}

// ---------------- epsilon head: edge part (256 edges/block) ----------------
__global__ __launch_bounds__(256,2) void k_eps_edge(
    const unsigned short* __restrict__ hb, const float* __restrict__ xbuf,
    const int* __restrict__ rowi, const int* __restrict__ coli,
    const unsigned short* __restrict__ blob,
    const float* __restrict__ bem2v, const float* __restrict__ bec1v,
    const float* __restrict__ Wec2, const float* __restrict__ bec2,
    float* __restrict__ epsb)
{
  __shared__ struct {
    alignas(16) unsigned char wbuf[2][16384];
    int row[256], col[256];
    float rel[256][3]; float dist[256];
    float b2[128], bc1[128], wc[3][128];
  } sm;
  const int tid = threadIdx.x, lane = tid & 63, w = tid >> 6, q = lane >> 4;
  const int q8 = q << 3;
  const int ebase = blockIdx.x << 8;
  {
    const int e = ebase + tid;
    const int r = rowi[e], c = coli[e];
    sm.row[tid]=r; sm.col[tid]=c;
    const float dx = xbuf[3*r+0]-xbuf[3*c+0];
    const float dy = xbuf[3*r+1]-xbuf[3*c+1];
    const float dz = xbuf[3*r+2]-xbuf[3*c+2];
    sm.rel[tid][0]=dx; sm.rel[tid][1]=dy; sm.rel[tid][2]=dz;
    sm.dist[tid] = sqrtf(dx*dx+dy*dy+dz*dz);
  }
  if (tid < 128){
    sm.b2[tid]=bem2v[tid]; sm.bc1[tid]=bec1v[tid];
    sm.wc[0][tid]=Wec2[tid*3+0]; sm.wc[1][tid]=Wec2[tid*3+1]; sm.wc[2][tid]=Wec2[tid*3+2];
  }
  STG2(0,0); STG2(2,1);
  __syncthreads();

  const int toff = ((lane&15)<<6) + ((q ^ ((lane>>1)&3))<<4);
  int rn[4], cn[4];
  #pragma unroll
  for (int e=0;e<4;++e){
    const int el = (w<<6) + (e<<4) + (lane&15);
    rn[e] = sm.row[el]; cn[e] = sm.col[el];
  }
  s16x8 BA[4][2], BB[4][2];
  #pragma unroll
  for (int e=0;e<4;++e){
    const int el = (w<<6) + (e<<4) + (lane&15);
    s16x8 bx = {0,0,0,0,0,0,0,0};
    if (q == 0){
      bx[0] = (short)f2b(sm.rel[el][0]);
      bx[1] = (short)f2b(sm.rel[el][1]);
      bx[2] = (short)f2b(sm.rel[el][2]);
      bx[3] = (short)f2b(sm.dist[el]);
      bx[4] = (short)0x3F80;
    }
    BA[e][0] = bx;
    BA[e][1] = *(const s16x8*)(hb + ((size_t)rn[e]<<7) + q8);
  }
  f32x4 acc[4][8] = {};

  BARF;
  #pragma unroll
  for (int e=0;e<4;++e){
    BB[e][0] = *(const s16x8*)(hb + ((size_t)rn[e]<<7) + 32 + q8);
    BB[e][1] = *(const s16x8*)(hb + ((size_t)rn[e]<<7) + 64 + q8);
  }
  PH2(0, BA[e][ti], acc);
  EBAR; STG2(4,0);
  BARF;
  #pragma unroll
  for (int e=0;e<4;++e){
    BA[e][0] = *(const s16x8*)(hb + ((size_t)rn[e]<<7) + 96 + q8);
    BA[e][1] = *(const s16x8*)(hb + ((size_t)cn[e]<<7) + q8);
  }
  PH2(1, BB[e][ti], acc);
  EBAR; STG2(6,1);
  WAITV(12); BARF;
  #pragma unroll
  for (int e=0;e<4;++e){
    BB[e][0] = *(const s16x8*)(hb + ((size_t)cn[e]<<7) + 32 + q8);
    BB[e][1] = *(const s16x8*)(hb + ((size_t)cn[e]<<7) + 64 + q8);
  }
  PH2(0, BA[e][ti], acc);
  EBAR; STG1(8,0);
  WAITV(10); BARF;
  #pragma unroll
  for (int e=0;e<4;++e)
    BA[e][0] = *(const s16x8*)(hb + ((size_t)cn[e]<<7) + 96 + q8);
  PH2(1, BB[e][ti], acc);
  EBAR; STG2(9,1);
  WAITV(8); BARF;
  PH1(0, BA[e][0], acc);
  EBAR; STG2(11,0);

  s16x8 sb[4][4];
  #pragma unroll
  for (int e=0;e<4;++e)
    #pragma unroll
    for (int c=0;c<4;++c) sb[e][c] = siluPack(acc[e][2*c], acc[e][2*c+1]);
  f32x4 acc2[4][8];
  #pragma unroll
  for (int s=0;s<8;++s){
    const f32x4 b = *(const f32x4*)&sm.b2[(s<<4)+(q<<2)];
    #pragma unroll
    for (int e=0;e<4;++e) acc2[e][s] = b;
  }
  WAITV(4); BARF;
  PH2(1, sb[e][ti], acc2);
  EBAR; STG2(13,1);
  WAITV(4); BARF;
  PH2(0, sb[e][2+ti], acc2);
  EBAR; STG2(15,0);

  s16x8 mb[4][4];
  #pragma unroll
  for (int e=0;e<4;++e)
    #pragma unroll
    for (int c=0;c<4;++c) mb[e][c] = siluPack(acc2[e][2*c], acc2[e][2*c+1]);
  f32x4 acc3[4][8];
  #pragma unroll
  for (int s=0;s<8;++s){
    const f32x4 b = *(const f32x4*)&sm.bc1[(s<<4)+(q<<2)];
    #pragma unroll
    for (int e=0;e<4;++e) acc3[e][s] = b;
  }
  WAITV(4); BARF;
  PH2(1, mb[e][ti], acc3);
  EBAR;
  WAITV(0); BARF;
  PH2(0, mb[e][2+ti], acc3);

  float d0[4]={0,0,0,0}, d1[4]={0,0,0,0}, d2[4]={0,0,0,0};
  #pragma unroll
  for (int s=0;s<8;++s){
    const f32x4 w0 = *(const f32x4*)&sm.wc[0][(s<<4)+(q<<2)];
    const f32x4 w1 = *(const f32x4*)&sm.wc[1][(s<<4)+(q<<2)];
    const f32x4 w2 = *(const f32x4*)&sm.wc[2][(s<<4)+(q<<2)];
    #pragma unroll
    for (int e=0;e<4;++e)
      #pragma unroll
      for (int r=0;r<4;++r){
        const float ev = silu_f(acc3[e][s][r]);
        d0[e] += ev*w0[r]; d1[e] += ev*w1[r]; d2[e] += ev*w2[r];
      }
  }
  #pragma unroll
  for (int e=0;e<4;++e){
    d0[e] += __shfl_xor(d0[e],16); d0[e] += __shfl_xor(d0[e],32);
    d1[e] += __shfl_xor(d1[e],16); d1[e] += __shfl_xor(d1[e],32);
    d2[e] += __shfl_xor(d2[e],16); d2[e] += __shfl_xor(d2[e],32);
    if (q < 3){
      const float val = (q==0)?d0[e]:((q==1)?d1[e]:d2[e]);
      atomicAdd(&epsb[(size_t)cn[e]*3 + q], val + bec2[q]);
    }
  }
}

// ---------------- epsilon head: node part ----------------
__global__ __launch_bounds__(256) void k_eps_node(
    const float* __restrict__ hbuf, const float* __restrict__ xbuf,
    const unsigned short* __restrict__ Wh1T, const float* __restrict__ bh1v,
    const float* __restrict__ wh1_rows,
    const float* __restrict__ Wh2, const float* __restrict__ bh2,
    float* __restrict__ epsb)
{
  __shared__ float s_bh1[128], s_w3[3][128], s_wc[3][128];
  const int tid = threadIdx.x;
  if (tid >= 128){
    const int f = tid - 128;
    s_bh1[f]=bh1v[f];
    s_w3[0][f]=wh1_rows[f]; s_w3[1][f]=wh1_rows[128+f]; s_w3[2][f]=wh1_rows[256+f];
    s_wc[0][f]=Wh2[f*3+0]; s_wc[1][f]=Wh2[f*3+1]; s_wc[2][f]=Wh2[f*3+2];
  }
  __syncthreads();
  const int lane = tid & 63, q = lane >> 4;
  const int n = (blockIdx.x<<6) + ((tid>>6)<<4) + (lane & 15);
  const bool valid = n < N_NODES;
  const int nc = valid ? n : (N_NODES-1);
  const float* __restrict__ hp = hbuf + (size_t)nc*HDIM;
  const float x0 = xbuf[3*nc+0], x1 = xbuf[3*nc+1], x2 = xbuf[3*nc+2];
  f32x4 acc[8];
  #pragma unroll
  for (int s=0;s<8;++s)
    #pragma unroll
    for (int r=0;r<4;++r){
      const int f = (s<<4)+(q<<2)+r;
      acc[s][r] = s_bh1[f] + x0*s_w3[0][f] + x1*s_w3[1][f] + x2*s_w3[2][f];
    }
  #pragma unroll
  for (int kk=0;kk<4;++kk){
    const s16x8 bf = ldBf32(hp + (kk<<5), q);
    #pragma unroll
    for (int s=0;s<8;++s) acc[s] = MFMA(ldA(Wh1T, 128, s, kk, lane), bf, acc[s]);
  }
  float d0=0.f, d1=0.f, d2=0.f;
  #pragma unroll
  for (int s=0;s<8;++s)
    #pragma unroll
    for (int r=0;r<4;++r){
      const int f = (s<<4)+(q<<2)+r;
      const float ev = silu_f(acc[s][r]);
      d0 += ev*s_wc[0][f]; d1 += ev*s_wc[1][f]; d2 += ev*s_wc[2][f];
    }
  d0 += __shfl_xor(d0,16); d0 += __shfl_xor(d0,32);
  d1 += __shfl_xor(d1,16); d1 += __shfl_xor(d1,32);
  d2 += __shfl_xor(d2,16); d2 += __shfl_xor(d2,32);
  if (valid && q < 3){
    const float val = (q==0)?d0:((q==1)?d1:d2);
    epsb[(size_t)n*3 + q] += val + bh2[q];
  }
}

extern "C" void kernel_launch(void* const* d_in, const int* in_sizes, int n_in,
                              void* d_out, int out_size, void* d_ws, size_t ws_size,
                              hipStream_t stream)
{
  (void)in_sizes; (void)n_in; (void)out_size;
  const float* h_in  = (const float*)d_in[0];
  const float* x_in  = (const float*)d_in[1];
  const int*   eidx  = (const int*)d_in[2];
  const float* W_emb = (const float*)d_in[3];
  const float* b_emb = (const float*)d_in[4];
  const float* Wm1 = (const float*)d_in[5];
  const float* bm1 = (const float*)d_in[6];
  const float* Wm2 = (const float*)d_in[7];
  const float* bm2 = (const float*)d_in[8];
  const float* Wc1 = (const float*)d_in[9];
  const float* bc1 = (const float*)d_in[10];
  const float* Wc2 = (const float*)d_in[11];
  const float* Wn1 = (const float*)d_in[12];
  const float* bn1 = (const float*)d_in[13];
  const float* Wn2 = (const float*)d_in[14];
  const float* bn2 = (const float*)d_in[15];
  const float* lng = (const float*)d_in[16];
  const float* lnb = (const float*)d_in[17];
  const float* Wem1 = (const float*)d_in[18];
  const float* bem1 = (const float*)d_in[19];
  const float* Wem2 = (const float*)d_in[20];
  const float* bem2 = (const float*)d_in[21];
  const float* Wec1 = (const float*)d_in[22];
  const float* bec1 = (const float*)d_in[23];
  const float* Wec2 = (const float*)d_in[24];
  const float* bec2 = (const float*)d_in[25];
  const float* Wh1 = (const float*)d_in[26];
  const float* bh1 = (const float*)d_in[27];
  const float* Wh2 = (const float*)d_in[28];
  const float* bh2 = (const float*)d_in[29];

  const int* rowi = eidx;
  const int* coli = eidx + N_EDGES;

  float* hbuf = (float*)d_out;
  float* xbuf = hbuf + (size_t)N_NODES*HDIM;
  float* epsb = xbuf + (size_t)N_NODES*3;

  char* wp = (char*)d_ws;
  auto alloc = [&](size_t bytes)->char*{
    char* p = wp; wp += (bytes + 255) & ~(size_t)255; return p;
  };
  unsigned short* WembT = (unsigned short*)alloc((size_t)128*64*2);
  unsigned short *Wn1T[NLAYERS], *Wn2T[NLAYERS];
  for (int i=0;i<NLAYERS;++i){
    Wn1T[i] = (unsigned short*)alloc((size_t)128*256*2);
    Wn2T[i] = (unsigned short*)alloc((size_t)128*128*2);
  }
  unsigned short* Wh1T  = (unsigned short*)alloc((size_t)128*128*2);
  unsigned short* blobL = (unsigned short*)alloc((size_t)NLAYERS*17*4096*2);
  unsigned short* blobE = (unsigned short*)alloc((size_t)17*4096*2);
  unsigned short* hb    = (unsigned short*)alloc((size_t)N_NODES*HDIM*2);
  int* degi   = (int*)alloc((size_t)N_NODES*4);
  int* offv   = (int*)alloc((size_t)N_NODES*4);
  int* cursor = (int*)alloc((size_t)N_NODES*4);
  int* bsum   = (int*)alloc(4096);
  float* cu   = (float*)alloc((size_t)N_NODES*3*4);
  int* perm   = (int*)alloc((size_t)N_EDGES*4);
  char* big   = alloc((size_t)N_EDGES*HDIM*2);       // m_buf (CSR) or agg (atomic)
  const bool use_csr = ((size_t)(wp - (char*)d_ws) <= ws_size);
  unsigned short* m_buf = (unsigned short*)big;
  float* agg = (float*)big;

  auto conv = [&](const float* W, unsigned short* WT, int kshift){
    const int tot = 128 << kshift;
    k_conv<<<dim3((tot+255)/256), dim3(256), 0, stream>>>(W, WT, kshift);
  };
  conv(W_emb, WembT, 6);
  for (int i=0;i<NLAYERS;++i){
    conv(Wn1 + (size_t)i*256*128, Wn1T[i], 8);
    conv(Wn2 + (size_t)i*128*128, Wn2T[i], 7);
  }
  conv(Wh1,  Wh1T,  7);
  const int cb_grid = (17*4096)/256;
  for (int i=0;i<NLAYERS;++i){
    const float* Wm1i = Wm1 + (size_t)i*257*128;
    k_conv_blob<<<dim3(cb_grid), dim3(256), 0, stream>>>(
        Wm1i, Wm2 + (size_t)i*128*128, Wc1 + (size_t)i*128*128,
        Wm1i + (size_t)256*128, bm1 + i*128, 1, blobL + (size_t)i*17*4096);
  }
  k_conv_blob<<<dim3(cb_grid), dim3(256), 0, stream>>>(
      Wem1, Wem2, Wec1, Wem1 + (size_t)256*128, bem1, 4, blobE);

  hipMemsetAsync(degi, 0, (size_t)N_NODES*4, stream);
  k_degree<<<dim3((N_EDGES+255)/256), dim3(256), 0, stream>>>(coli, degi);
  const int nb = (N_NODES + 255)/256;
  if (use_csr){
    k_scanA<<<dim3(nb), dim3(256), 0, stream>>>(degi, offv, bsum);
    k_scanB<<<dim3(1), dim3(256), 0, stream>>>(bsum, nb);
    k_scanC<<<dim3(nb), dim3(256), 0, stream>>>(offv, bsum, cursor);
    k_fill<<<dim3((N_EDGES+255)/256), dim3(256), 0, stream>>>(coli, cursor, perm);
  }
  k_xcopy<<<dim3((N_NODES*3+255)/256), dim3(256), 0, stream>>>(x_in, xbuf);
  k_embed<<<dim3((N_NODES+63)/64), dim3(256), 0, stream>>>(h_in, WembT, b_emb, hbuf, hb);

  for (int i=0;i<NLAYERS;++i){
    hipMemsetAsync(cu, 0, (size_t)N_NODES*3*4, stream);
    if (!use_csr) hipMemsetAsync(agg, 0, (size_t)N_NODES*HDIM*4, stream);
    const unsigned short* blob_i = blobL + (size_t)i*17*4096;
    if (use_csr){
      k_edge_mlp<true><<<dim3(N_EDGES/256), dim3(256), 0, stream>>>(
        hb, xbuf, rowi, coli, perm, blob_i,
        bm2 + i*128, bc1 + i*128, Wc2 + i*128, m_buf, agg, cu);
      k_node_mlp<true><<<dim3((N_NODES+63)/64), dim3(256), 0, stream>>>(
        hbuf, hb, xbuf, m_buf, agg, offv, degi, cu,
        Wn1T[i], bn1 + i*128, Wn2T[i], bn2 + i*128, lng + i*128, lnb + i*128);
    } else {
      k_edge_mlp<false><<<dim3(N_EDGES/256), dim3(256), 0, stream>>>(
        hb, xbuf, rowi, coli, perm, blob_i,
        bm2 + i*128, bc1 + i*128, Wc2 + i*128, m_buf, agg, cu);
      k_node_mlp<false><<<dim3((N_NODES+63)/64), dim3(256), 0, stream>>>(
        hbuf, hb, xbuf, m_buf, agg, offv, degi, cu,
        Wn1T[i], bn1 + i*128, Wn2T[i], bn2 + i*128, lng + i*128, lnb + i*128);
    }
  }
  hipMemsetAsync(epsb, 0, (size_t)N_NODES*3*4, stream);
  k_eps_edge<<<dim3(N_EDGES/256), dim3(256), 0, stream>>>(
    hb, xbuf, rowi, coli, blobE, bem2, bec1, Wec2, bec2, epsb);
  k_eps_node<<<dim3((N_NODES+63)/64), dim3(256), 0, stream>>>(
    hbuf, xbuf, Wh1T, bh1, Wh1 + (size_t)128*128, Wh2, bh2, epsb);
}